// Round 6
// baseline (1410.798 us; speedup 1.0000x reference)
//
#include <hip/hip_runtime.h>
#include <hip/hip_bf16.h>
#include <math.h>

#define LB256 __launch_bounds__(256)

#define NB_SHIFT 7
#define NB_ROWS  (1 << NB_SHIFT)   // 128 rows per bucket
#define GA 256                     // blocks for hist/bucket-scatter (keeps scan <= 64 blocks)

// ---------------- hierarchical exclusive scan ----------------
template <int PT>
__global__ LB256 void gscan_sum(const int* __restrict__ a, int n, int* __restrict__ bsum) {
    int base = blockIdx.x * (256 * PT);
    int sum = 0;
    for (int i = threadIdx.x; i < 256 * PT; i += 256) {
        int idx = base + i;
        sum += (idx < n) ? a[idx] : 0;
    }
#pragma unroll
    for (int o = 32; o; o >>= 1) sum += __shfl_down(sum, o);
    __shared__ int ws[4];
    if ((threadIdx.x & 63) == 0) ws[threadIdx.x >> 6] = sum;
    __syncthreads();
    if (threadIdx.x == 0) bsum[blockIdx.x] = ws[0] + ws[1] + ws[2] + ws[3];
}

__global__ void gscan_offsets(const int* __restrict__ bsum, int nbk, int* __restrict__ boff) {
    int lane = threadIdx.x;
    int v = (lane < nbk) ? bsum[lane] : 0;
    int orig = v;
#pragma unroll
    for (int o = 1; o < 64; o <<= 1) {
        int u = __shfl_up(v, o);
        if (lane >= o) v += u;
    }
    if (lane < nbk) boff[lane] = v - orig;  // exclusive
}

template <int PT>
__global__ LB256 void gscan_scatter(const int* __restrict__ a, int n,
                                    const int* __restrict__ boff, int total,
                                    int* __restrict__ out1) {
    int base = blockIdx.x * (256 * PT);
    int idx0 = base + threadIdx.x * PT;
    int vals[PT];
    int s = 0;
#pragma unroll
    for (int k = 0; k < PT; ++k) {
        int id = idx0 + k;
        vals[k] = (id < n) ? a[id] : 0;
        s += vals[k];
    }
    int lane = threadIdx.x & 63, wid = threadIdx.x >> 6;
    int inc = s;
#pragma unroll
    for (int o = 1; o < 64; o <<= 1) {
        int u = __shfl_up(inc, o);
        if (lane >= o) inc += u;
    }
    __shared__ int wsum[4];
    if (lane == 63) wsum[wid] = inc;
    __syncthreads();
    int woff = 0;
    for (int i = 0; i < wid; ++i) woff += wsum[i];
    int excl = inc - s + woff + boff[blockIdx.x];
#pragma unroll
    for (int k = 0; k < PT; ++k) {
        int id = idx0 + k;
        if (id < n) out1[id] = excl;
        excl += vals[k];
    }
    if (blockIdx.x == 0 && threadIdx.x == 0) out1[n] = total;
}

// ---------------- bucket sort (no global atomics) ----------------

__global__ LB256 void hist_kernel(const int* __restrict__ row, int E, int nb, int chunk,
                                  int* __restrict__ countmat) {
    __shared__ int lh[1024];
    for (int b = threadIdx.x; b < nb; b += 256) lh[b] = 0;
    __syncthreads();
    int beg = blockIdx.x * chunk;
    int end = min(E, beg + chunk);
    for (int i = beg + threadIdx.x; i < end; i += 256)
        atomicAdd(&lh[row[i] >> NB_SHIFT], 1);
    __syncthreads();
    for (int b = threadIdx.x; b < nb; b += 256)
        countmat[b * gridDim.x + blockIdx.x] = lh[b];
}

// entry = (col | rowlocal<<17, w); col < 2^17, rowlocal < 2^7
__global__ LB256 void bucket_scatter_kernel(const int* __restrict__ row, const int* __restrict__ col,
                                            const float* __restrict__ w, const int* __restrict__ off,
                                            int E, int nb, int chunk, float2* __restrict__ tmp) {
    __shared__ int lc[1024];
    __shared__ int loff[1024];
    for (int b = threadIdx.x; b < nb; b += 256) {
        lc[b] = 0;
        loff[b] = off[b * gridDim.x + blockIdx.x];
    }
    __syncthreads();
    int beg = blockIdx.x * chunk;
    int end = min(E, beg + chunk);
    for (int i = beg + threadIdx.x; i < end; i += 256) {
        int r = row[i];
        int b = r >> NB_SHIFT;
        int lpos = atomicAdd(&lc[b], 1);
        unsigned pk = (unsigned)col[i] | ((unsigned)(r & (NB_ROWS - 1)) << 17);
        tmp[loff[b] + lpos] = make_float2(__int_as_float((int)pk), w[i]);
    }
}

// per-bucket inverse degree (layer-invariant)
__global__ LB256 void invdeg_kernel(const int* __restrict__ offm, int G,
                                    const float2* __restrict__ tmp,
                                    float* __restrict__ inv, int N) {
    __shared__ int lcnt[NB_ROWS];
    int bk = blockIdx.x, tid = threadIdx.x;
    int s0 = offm[bk * G], e0 = offm[(bk + 1) * G];
    if (tid < NB_ROWS) lcnt[tid] = 0;
    __syncthreads();
    for (int j = s0 + tid; j < e0; j += 256)
        atomicAdd(&lcnt[(unsigned)__float_as_int(tmp[j].x) >> 17], 1);
    __syncthreads();
    int v = (bk << NB_SHIFT) + tid;
    if (tid < NB_ROWS && v < N) {
        int c = lcnt[tid];
        inv[v] = c ? 1.0f / (float)c : 0.0f;
    }
}

// ---------------- per-layer kernels ----------------

// t[v][f] = bf16( sum_k h[v][k] * W[f][k] )
template <int FIN, int FOUT>
__global__ LB256 void transform_kernel(const float* __restrict__ h, const float* __restrict__ W,
                                       __hip_bfloat16* __restrict__ t, int n) {
    int i = blockIdx.x * blockDim.x + threadIdx.x;
    if (i >= n * FOUT) return;
    int v = i / FOUT;
    int f = i % FOUT;
    float s = 0.0f;
#pragma unroll
    for (int k = 0; k < FIN; ++k) s = fmaf(h[v * FIN + k], W[f * FIN + k], s);
    t[i] = __float2bfloat16(s);
}

// per-bucket LDS-accumulated aggregation + fused residual/finalize
template <int F>
__global__ LB256 void agg_kernel(const int* __restrict__ offm, int G,
                                 const float2* __restrict__ tmp,
                                 const __hip_bfloat16* __restrict__ t,
                                 const float* __restrict__ b,
                                 const float* __restrict__ inv,
                                 float* __restrict__ h, int N) {
    __shared__ float acc[NB_ROWS * F];
    int bk = blockIdx.x;
    int tid = threadIdx.x;
    int s0 = offm[bk * G];
    int e0 = offm[(bk + 1) * G];
    int rbase = bk << NB_SHIFT;
    for (int k = tid; k < NB_ROWS * F; k += 256) acc[k] = 0.0f;
    __syncthreads();

    int f = tid % F;
    int g = tid / F;
    const int ng = 256 / F;
    float bf = b[f];
    int len = e0 - s0;
    const float2* base = tmp + s0;

    int j = g;
    for (; j + 7 * ng < len; j += 8 * ng) {
        float2 c[8];
#pragma unroll
        for (int u = 0; u < 8; ++u) c[u] = base[j + u * ng];
        float tv[8];
#pragma unroll
        for (int u = 0; u < 8; ++u) {
            unsigned p = (unsigned)__float_as_int(c[u].x);
            tv[u] = __bfloat162float(t[(p & 0x1FFFF) * F + f]);
        }
#pragma unroll
        for (int u = 0; u < 8; ++u) {
            unsigned p = (unsigned)__float_as_int(c[u].x);
            float m = fmaf(c[u].y, tv[u], bf);
            m = (m > 0.0f) ? m : 0.01f * m;
            atomicAdd(&acc[(p >> 17) * F + f], m);
        }
    }
    for (; j < len; j += ng) {
        float2 cc = base[j];
        unsigned p = (unsigned)__float_as_int(cc.x);
        float m = fmaf(cc.y, __bfloat162float(t[(p & 0x1FFFF) * F + f]), bf);
        m = (m > 0.0f) ? m : 0.01f * m;
        atomicAdd(&acc[(p >> 17) * F + f], m);
    }
    __syncthreads();

    int nrows = min(NB_ROWS, N - rbase);
    for (int k = tid; k < nrows * F; k += 256) {
        int row = k / F, ff = k % F;
        int v = rbase + row;
        float r = __bfloat162float(t[v * F + ff]) + b[ff];
        r = (r > 0.0f) ? r : 0.01f * r;
        h[v * F + ff] = acc[k] * inv[v] + r;
    }
}

// ---------------- head ----------------

__global__ LB256 void pool_kernel(const float* __restrict__ h, float* __restrict__ pool, int n) {
    __shared__ float ls[256];
    int f = threadIdx.x & 31;
    int grp = threadIdx.x >> 5;
    int gid = blockIdx.x * (blockDim.x >> 5) + grp;
    int ngrp = (blockDim.x >> 5) * gridDim.x;
    float s = 0.0f;
    for (int v = gid; v < n; v += ngrp) s += h[v * 32 + f];
    ls[threadIdx.x] = s;
    __syncthreads();
    if (threadIdx.x < 32) {
        float tot = 0.0f;
#pragma unroll
        for (int g = 0; g < 8; ++g) tot += ls[g * 32 + threadIdx.x];
        atomicAdd(&pool[threadIdx.x], tot);
    }
}

__global__ void head_kernel(const float* __restrict__ pool, const float* __restrict__ W7,
                            const float* __restrict__ b7, float* __restrict__ out, int n) {
    if (threadIdx.x != 0 || blockIdx.x != 0) return;
    float invn = 1.0f / (float)n;
    float l0 = b7[0], l1 = b7[1];
    for (int f = 0; f < 32; ++f) {
        float p = pool[f] * invn;
        l0 = fmaf(p, W7[f], l0);
        l1 = fmaf(p, W7[32 + f], l1);
    }
    float m = fmaxf(l0, l1);
    float lse = m + logf(expf(l0 - m) + expf(l1 - m));
    out[0] = l0 - lse;
    out[1] = l1 - lse;
}

// ---------------- launch ----------------

extern "C" void kernel_launch(void* const* d_in, const int* in_sizes, int n_in,
                              void* d_out, int out_size, void* d_ws, size_t ws_size,
                              hipStream_t stream) {
    const float* x  = (const float*)d_in[0];
    const int* edge = (const int*)d_in[1];
    const float* w  = (const float*)d_in[2];
    const float* W1 = (const float*)d_in[3];
    const float* b1 = (const float*)d_in[4];
    const float* W3 = (const float*)d_in[5];
    const float* b3 = (const float*)d_in[6];
    const float* W5 = (const float*)d_in[7];
    const float* b5 = (const float*)d_in[8];
    const float* W7 = (const float*)d_in[9];
    const float* b7 = (const float*)d_in[10];
    float* out = (float*)d_out;

    const int N = in_sizes[0] / 4;
    const int E = in_sizes[1] / 2;
    const int* row = edge;
    const int* col = edge + E;

    const int nb = (N + NB_ROWS - 1) >> NB_SHIFT;    // 782 buckets of 128 rows
    const int G = GA;
    const int chunk = (E + G - 1) / G;
    const int M = nb * G;                            // ~200k

    char* ws = (char*)d_ws;
    size_t off8 = 0;
    auto alloc = [&](size_t bytes) {
        void* p = ws + off8;
        off8 += (bytes + 255) & ~(size_t)255;
        return p;
    };
    int*    bsum     = (int*)alloc(256 * 4);
    int*    boff     = (int*)alloc(256 * 4);
    int*    countmat = (int*)alloc((size_t)M * 4);
    int*    offm     = (int*)alloc(((size_t)M + 1) * 4);
    float*  inv      = (float*)alloc((size_t)N * 4);
    float*  pool     = (float*)alloc(32 * 4);
    float2* tmp      = (float2*)alloc((size_t)E * 8);           // persists across layers
    __hip_bfloat16* t = (__hip_bfloat16*)alloc((size_t)N * 32 * 2);
    float*  h        = (float*)alloc((size_t)N * 32 * 4);
    (void)ws_size;

    hipMemsetAsync(pool, 0, 32 * 4, stream);

    const int B = 256;
    const int nbkM = (M + 4095) / 4096;       // 49 <= 64

    // bucket sort of edges (no global atomics)
    hist_kernel<<<G, B, 0, stream>>>(row, E, nb, chunk, countmat);
    gscan_sum<16><<<nbkM, B, 0, stream>>>(countmat, M, bsum);
    gscan_offsets<<<1, 64, 0, stream>>>(bsum, nbkM, boff);
    gscan_scatter<16><<<nbkM, B, 0, stream>>>(countmat, M, boff, E, offm);
    bucket_scatter_kernel<<<G, B, 0, stream>>>(row, col, w, offm, E, nb, chunk, tmp);
    invdeg_kernel<<<nb, B, 0, stream>>>(offm, G, tmp, inv, N);

    // ---- block 1: 4 -> 8 ----
    transform_kernel<4, 8><<<(N * 8 + B - 1) / B, B, 0, stream>>>(x, W1, t, N);
    agg_kernel<8><<<nb, B, 0, stream>>>(offm, G, tmp, t, b1, inv, h, N);

    // ---- block 2: 8 -> 16 ----
    transform_kernel<8, 16><<<(N * 16 + B - 1) / B, B, 0, stream>>>(h, W3, t, N);
    agg_kernel<16><<<nb, B, 0, stream>>>(offm, G, tmp, t, b3, inv, h, N);

    // ---- block 3: 16 -> 32 ----
    transform_kernel<16, 32><<<(N * 32 + B - 1) / B, B, 0, stream>>>(h, W5, t, N);
    agg_kernel<32><<<nb, B, 0, stream>>>(offm, G, tmp, t, b5, inv, h, N);

    // ---- head ----
    pool_kernel<<<256, B, 0, stream>>>(h, pool, N);
    head_kernel<<<1, 64, 0, stream>>>(pool, W7, b7, out, N);
}

// Round 8
// 454.931 us; speedup vs baseline: 3.1011x; 3.1011x over previous
//
#include <hip/hip_runtime.h>
#include <hip/hip_bf16.h>
#include <math.h>

// NOTE: identical logic to round-7 submission; that round died on an infra
// failure (container), not a kernel defect. Resubmitting for a clean bench.

#define LB256 __launch_bounds__(256)

#define NB_SHIFT 8
#define NB_ROWS  (1 << NB_SHIFT)   // 256 rows per bucket
#define GA 512                     // blocks for hist/bucket-scatter passes

// ---------------- hierarchical exclusive scan ----------------
template <int PT>
__global__ LB256 void gscan_sum(const int* __restrict__ a, int n, int* __restrict__ bsum) {
    int base = blockIdx.x * (256 * PT);
    int sum = 0;
    for (int i = threadIdx.x; i < 256 * PT; i += 256) {
        int idx = base + i;
        sum += (idx < n) ? a[idx] : 0;
    }
#pragma unroll
    for (int o = 32; o; o >>= 1) sum += __shfl_down(sum, o);
    __shared__ int ws[4];
    if ((threadIdx.x & 63) == 0) ws[threadIdx.x >> 6] = sum;
    __syncthreads();
    if (threadIdx.x == 0) bsum[blockIdx.x] = ws[0] + ws[1] + ws[2] + ws[3];
}

__global__ void gscan_offsets(const int* __restrict__ bsum, int nbk, int* __restrict__ boff) {
    int lane = threadIdx.x;
    int v = (lane < nbk) ? bsum[lane] : 0;
    int orig = v;
#pragma unroll
    for (int o = 1; o < 64; o <<= 1) {
        int u = __shfl_up(v, o);
        if (lane >= o) v += u;
    }
    if (lane < nbk) boff[lane] = v - orig;  // exclusive
}

template <int PT>
__global__ LB256 void gscan_scatter(const int* __restrict__ a, int n,
                                    const int* __restrict__ boff, int total,
                                    int* __restrict__ out1) {
    int base = blockIdx.x * (256 * PT);
    int idx0 = base + threadIdx.x * PT;
    int vals[PT];
    int s = 0;
#pragma unroll
    for (int k = 0; k < PT; ++k) {
        int id = idx0 + k;
        vals[k] = (id < n) ? a[id] : 0;
        s += vals[k];
    }
    int lane = threadIdx.x & 63, wid = threadIdx.x >> 6;
    int inc = s;
#pragma unroll
    for (int o = 1; o < 64; o <<= 1) {
        int u = __shfl_up(inc, o);
        if (lane >= o) inc += u;
    }
    __shared__ int wsum[4];
    if (lane == 63) wsum[wid] = inc;
    __syncthreads();
    int woff = 0;
    for (int i = 0; i < wid; ++i) woff += wsum[i];
    int excl = inc - s + woff + boff[blockIdx.x];
#pragma unroll
    for (int k = 0; k < PT; ++k) {
        int id = idx0 + k;
        if (id < n) out1[id] = excl;
        excl += vals[k];
    }
    if (blockIdx.x == 0 && threadIdx.x == 0) out1[n] = total;
}

// ---------------- CSR build (no global atomics) ----------------

__global__ LB256 void hist_kernel(const int* __restrict__ row, int E, int nb, int chunk,
                                  int* __restrict__ countmat) {
    __shared__ int lh[512];
    for (int b = threadIdx.x; b < nb; b += 256) lh[b] = 0;
    __syncthreads();
    int beg = blockIdx.x * chunk;
    int end = min(E, beg + chunk);
    for (int i = beg + threadIdx.x; i < end; i += 256)
        atomicAdd(&lh[row[i] >> NB_SHIFT], 1);
    __syncthreads();
    for (int b = threadIdx.x; b < nb; b += 256)
        countmat[b * gridDim.x + blockIdx.x] = lh[b];
}

// entry = (col | rowlocal<<17, w)
__global__ LB256 void bucket_scatter_kernel(const int* __restrict__ row, const int* __restrict__ col,
                                            const float* __restrict__ w, const int* __restrict__ off,
                                            int E, int nb, int chunk, float2* __restrict__ tmp) {
    __shared__ int lc[512];
    __shared__ int loff[512];
    for (int b = threadIdx.x; b < nb; b += 256) {
        lc[b] = 0;
        loff[b] = off[b * gridDim.x + blockIdx.x];
    }
    __syncthreads();
    int beg = blockIdx.x * chunk;
    int end = min(E, beg + chunk);
    for (int i = beg + threadIdx.x; i < end; i += 256) {
        int r = row[i];
        int b = r >> NB_SHIFT;
        int lpos = atomicAdd(&lc[b], 1);
        unsigned pk = (unsigned)col[i] | ((unsigned)(r & (NB_ROWS - 1)) << 17);
        tmp[loff[b] + lpos] = make_float2(__int_as_float((int)pk), w[i]);
    }
}

// one block per bucket: LDS histogram -> block scan -> rowptr + LDS-cursor scatter
__global__ LB256 void csr_build_kernel(const float2* __restrict__ tmp, const int* __restrict__ off,
                                       int G, int N, int E,
                                       int* __restrict__ rowptr, float2* __restrict__ csr) {
    __shared__ int lcnt[NB_ROWS];
    __shared__ int wsum[4];
    int b = blockIdx.x;
    int tid = threadIdx.x;
    int s0 = off[b * G];
    int e0 = off[(b + 1) * G];
    int rbase = b << NB_SHIFT;

    lcnt[tid] = 0;
    __syncthreads();
    for (int j = s0 + tid; j < e0; j += 256) {
        unsigned p = (unsigned)__float_as_int(tmp[j].x);
        atomicAdd(&lcnt[p >> 17], 1);
    }
    __syncthreads();

    int v = lcnt[tid];
    int lane = tid & 63, wid = tid >> 6;
    int inc = v;
#pragma unroll
    for (int o = 1; o < 64; o <<= 1) {
        int u = __shfl_up(inc, o);
        if (lane >= o) inc += u;
    }
    if (lane == 63) wsum[wid] = inc;
    __syncthreads();
    int woff = 0;
    for (int i = 0; i < wid; ++i) woff += wsum[i];
    int ex = inc - v + woff;

    int idx = rbase + tid;
    if (idx < N) rowptr[idx] = s0 + ex;
    if (b == gridDim.x - 1 && tid == 0) rowptr[N] = E;
    __syncthreads();
    lcnt[tid] = ex;  // cursors
    __syncthreads();

    for (int j = s0 + tid; j < e0; j += 256) {
        float2 c = tmp[j];
        unsigned p = (unsigned)__float_as_int(c.x);
        int pos = s0 + atomicAdd(&lcnt[p >> 17], 1);
        csr[pos] = make_float2(__int_as_float((int)(p & 0x1FFFF)), c.y);
    }
}

// ---------------- per-layer kernels ----------------

// t (bf16) = h @ W^T, feature-split into halves of FH=min(FOUT,16)
template <int FIN, int FOUT>
__global__ LB256 void transform_kernel(const float* __restrict__ h, const float* __restrict__ W,
                                       __hip_bfloat16* __restrict__ t0,
                                       __hip_bfloat16* __restrict__ t1, int n) {
    constexpr int FH = (FOUT > 16) ? 16 : FOUT;
    int i = blockIdx.x * blockDim.x + threadIdx.x;
    if (i >= n * FOUT) return;
    int v = i / FOUT;
    int f = i % FOUT;
    float s = 0.0f;
#pragma unroll
    for (int k = 0; k < FIN; ++k) s = fmaf(h[v * FIN + k], W[f * FIN + k], s);
    __hip_bfloat16 bv = __float2bfloat16(s);
    if (f < FH) t0[v * FH + f] = bv;
    else        t1[v * FH + (f - FH)] = bv;
}

// gather-side aggregation over one 16-or-8-feature half; lane owns 2 features.
template <int FH, int FTOT>
__global__ LB256 void agg_half_kernel(const int* __restrict__ rowptr,
                                      const float2* __restrict__ csr,
                                      const unsigned* __restrict__ th,  // [N][FH/2] bf16x2
                                      const float* __restrict__ b, int fo,
                                      float* __restrict__ h, int N) {
    constexpr int GS = FH / 2;        // lanes per group
    constexpr int RPB = 256 / GS;     // rows per block
    int g = threadIdx.x / GS;
    int l = threadIdx.x % GS;
    int v = blockIdx.x * RPB + g;
    if (v >= N) return;
    int beg = rowptr[v], end = rowptr[v + 1];
    float bf0 = b[fo + 2 * l];
    float bf1 = b[fo + 2 * l + 1];
    float a0 = 0.0f, a1 = 0.0f;
    const unsigned long long* cp = (const unsigned long long*)csr;

    int j = beg;
    for (; j + 3 < end; j += 4) {
        unsigned long long e0 = __builtin_nontemporal_load(&cp[j]);
        unsigned long long e1 = __builtin_nontemporal_load(&cp[j + 1]);
        unsigned long long e2 = __builtin_nontemporal_load(&cp[j + 2]);
        unsigned long long e3 = __builtin_nontemporal_load(&cp[j + 3]);
        unsigned c0 = (unsigned)e0 & 0x1FFFFu, c1 = (unsigned)e1 & 0x1FFFFu;
        unsigned c2 = (unsigned)e2 & 0x1FFFFu, c3 = (unsigned)e3 & 0x1FFFFu;
        unsigned t0 = th[c0 * GS + l];
        unsigned t1 = th[c1 * GS + l];
        unsigned t2 = th[c2 * GS + l];
        unsigned t3 = th[c3 * GS + l];
        float w0 = __uint_as_float((unsigned)(e0 >> 32));
        float w1 = __uint_as_float((unsigned)(e1 >> 32));
        float w2 = __uint_as_float((unsigned)(e2 >> 32));
        float w3 = __uint_as_float((unsigned)(e3 >> 32));
        float m;
        m = fmaf(w0, __uint_as_float(t0 << 16), bf0);         a0 += (m > 0.f) ? m : 0.01f * m;
        m = fmaf(w0, __uint_as_float(t0 & 0xffff0000u), bf1); a1 += (m > 0.f) ? m : 0.01f * m;
        m = fmaf(w1, __uint_as_float(t1 << 16), bf0);         a0 += (m > 0.f) ? m : 0.01f * m;
        m = fmaf(w1, __uint_as_float(t1 & 0xffff0000u), bf1); a1 += (m > 0.f) ? m : 0.01f * m;
        m = fmaf(w2, __uint_as_float(t2 << 16), bf0);         a0 += (m > 0.f) ? m : 0.01f * m;
        m = fmaf(w2, __uint_as_float(t2 & 0xffff0000u), bf1); a1 += (m > 0.f) ? m : 0.01f * m;
        m = fmaf(w3, __uint_as_float(t3 << 16), bf0);         a0 += (m > 0.f) ? m : 0.01f * m;
        m = fmaf(w3, __uint_as_float(t3 & 0xffff0000u), bf1); a1 += (m > 0.f) ? m : 0.01f * m;
    }
    for (; j < end; ++j) {
        unsigned long long e0 = __builtin_nontemporal_load(&cp[j]);
        unsigned c0 = (unsigned)e0 & 0x1FFFFu;
        unsigned t0 = th[c0 * GS + l];
        float w0 = __uint_as_float((unsigned)(e0 >> 32));
        float m;
        m = fmaf(w0, __uint_as_float(t0 << 16), bf0);         a0 += (m > 0.f) ? m : 0.01f * m;
        m = fmaf(w0, __uint_as_float(t0 & 0xffff0000u), bf1); a1 += (m > 0.f) ? m : 0.01f * m;
    }

    int deg = end - beg;
    float iv = deg ? 1.0f / (float)deg : 0.0f;
    unsigned tr = th[v * GS + l];
    float r0 = __uint_as_float(tr << 16) + bf0;
    float r1 = __uint_as_float(tr & 0xffff0000u) + bf1;
    r0 = (r0 > 0.f) ? r0 : 0.01f * r0;
    r1 = (r1 > 0.f) ? r1 : 0.01f * r1;
    float2 st = make_float2(fmaf(a0, iv, r0), fmaf(a1, iv, r1));
    *(float2*)(h + (size_t)v * FTOT + fo + 2 * l) = st;
}

// ---------------- head ----------------

__global__ LB256 void pool_kernel(const float* __restrict__ h, float* __restrict__ pool, int n) {
    __shared__ float ls[256];
    int f = threadIdx.x & 31;
    int grp = threadIdx.x >> 5;
    int gid = blockIdx.x * (blockDim.x >> 5) + grp;
    int ngrp = (blockDim.x >> 5) * gridDim.x;
    float s = 0.0f;
    for (int v = gid; v < n; v += ngrp) s += h[v * 32 + f];
    ls[threadIdx.x] = s;
    __syncthreads();
    if (threadIdx.x < 32) {
        float tot = 0.0f;
#pragma unroll
        for (int g = 0; g < 8; ++g) tot += ls[g * 32 + threadIdx.x];
        atomicAdd(&pool[threadIdx.x], tot);
    }
}

__global__ void head_kernel(const float* __restrict__ pool, const float* __restrict__ W7,
                            const float* __restrict__ b7, float* __restrict__ out, int n) {
    if (threadIdx.x != 0 || blockIdx.x != 0) return;
    float invn = 1.0f / (float)n;
    float l0 = b7[0], l1 = b7[1];
    for (int f = 0; f < 32; ++f) {
        float p = pool[f] * invn;
        l0 = fmaf(p, W7[f], l0);
        l1 = fmaf(p, W7[32 + f], l1);
    }
    float m = fmaxf(l0, l1);
    float lse = m + logf(expf(l0 - m) + expf(l1 - m));
    out[0] = l0 - lse;
    out[1] = l1 - lse;
}

// ---------------- launch ----------------

extern "C" void kernel_launch(void* const* d_in, const int* in_sizes, int n_in,
                              void* d_out, int out_size, void* d_ws, size_t ws_size,
                              hipStream_t stream) {
    const float* x  = (const float*)d_in[0];
    const int* edge = (const int*)d_in[1];
    const float* w  = (const float*)d_in[2];
    const float* W1 = (const float*)d_in[3];
    const float* b1 = (const float*)d_in[4];
    const float* W3 = (const float*)d_in[5];
    const float* b3 = (const float*)d_in[6];
    const float* W5 = (const float*)d_in[7];
    const float* b5 = (const float*)d_in[8];
    const float* W7 = (const float*)d_in[9];
    const float* b7 = (const float*)d_in[10];
    float* out = (float*)d_out;

    const int N = in_sizes[0] / 4;
    const int E = in_sizes[1] / 2;
    const int* row = edge;
    const int* col = edge + E;

    const int nb = (N + NB_ROWS - 1) >> NB_SHIFT;    // 391 buckets
    const int G = GA;
    const int chunk = (E + G - 1) / G;
    const int M = nb * G;

    char* ws = (char*)d_ws;
    size_t off8 = 0;
    auto alloc = [&](size_t bytes) {
        void* p = ws + off8;
        off8 += (bytes + 255) & ~(size_t)255;
        return p;
    };
    int*    bsum     = (int*)alloc(256 * 4);
    int*    boff     = (int*)alloc(256 * 4);
    int*    countmat = (int*)alloc((size_t)M * 4);
    int*    offm     = (int*)alloc(((size_t)M + 1) * 4);
    int*    rowptr   = (int*)alloc(((size_t)N + 1) * 4);
    float*  pool     = (float*)alloc(32 * 4);
    float2* csr      = (float2*)alloc((size_t)E * 8);
    __hip_bfloat16* t0 = (__hip_bfloat16*)alloc((size_t)N * 16 * 2);
    __hip_bfloat16* t1 = (__hip_bfloat16*)alloc((size_t)N * 16 * 2);
    float*  h1       = (float*)alloc((size_t)N * 8 * 4);
    float*  h2       = (float*)alloc((size_t)N * 16 * 4);
    // tmp (E*8 = 25.6MB) overlaid with h3 (N*32*4 = 12.8MB): tmp dead before layers
    size_t bigsz = (size_t)E * 8;
    size_t h3sz  = (size_t)N * 32 * 4;
    char*  big   = (char*)alloc(bigsz > h3sz ? bigsz : h3sz);
    float2* tmp  = (float2*)big;
    float*  h3   = (float*)big;
    (void)ws_size;

    hipMemsetAsync(pool, 0, 32 * 4, stream);

    const int B = 256;
    const int nbkM = (M + 4095) / 4096;  // <= 64

    // CSR build
    hist_kernel<<<G, B, 0, stream>>>(row, E, nb, chunk, countmat);
    gscan_sum<16><<<nbkM, B, 0, stream>>>(countmat, M, bsum);
    gscan_offsets<<<1, 64, 0, stream>>>(bsum, nbkM, boff);
    gscan_scatter<16><<<nbkM, B, 0, stream>>>(countmat, M, boff, E, offm);
    bucket_scatter_kernel<<<G, B, 0, stream>>>(row, col, w, offm, E, nb, chunk, tmp);
    csr_build_kernel<<<nb, B, 0, stream>>>(tmp, offm, G, N, E, rowptr, csr);

    // ---- block 1: 4 -> 8 ----
    transform_kernel<4, 8><<<(N * 8 + B - 1) / B, B, 0, stream>>>(x, W1, t0, t0, N);
    agg_half_kernel<8, 8><<<(N + 63) / 64, B, 0, stream>>>(rowptr, csr, (const unsigned*)t0, b1, 0, h1, N);

    // ---- block 2: 8 -> 16 ----
    transform_kernel<8, 16><<<(N * 16 + B - 1) / B, B, 0, stream>>>(h1, W3, t0, t0, N);
    agg_half_kernel<16, 16><<<(N + 31) / 32, B, 0, stream>>>(rowptr, csr, (const unsigned*)t0, b3, 0, h2, N);

    // ---- block 3: 16 -> 32 (two independent 16-feature halves) ----
    transform_kernel<16, 32><<<(N * 32 + B - 1) / B, B, 0, stream>>>(h2, W5, t0, t1, N);
    agg_half_kernel<16, 32><<<(N + 31) / 32, B, 0, stream>>>(rowptr, csr, (const unsigned*)t0, b5, 0, h3, N);
    agg_half_kernel<16, 32><<<(N + 31) / 32, B, 0, stream>>>(rowptr, csr, (const unsigned*)t1, b5, 16, h3, N);

    // ---- head ----
    pool_kernel<<<256, B, 0, stream>>>(h3, pool, N);
    head_kernel<<<1, 64, 0, stream>>>(pool, W7, b7, out, N);
}

// Round 10
// 438.245 us; speedup vs baseline: 3.2192x; 1.0381x over previous
//
#include <hip/hip_runtime.h>
#include <hip/hip_bf16.h>
#include <math.h>

// NOTE: identical to round-9 submission — that round hit a GPU-acquisition
// timeout (infra), the kernel never executed. Resubmitting for a clean bench.

#define LB256 __launch_bounds__(256)

#define NB_SHIFT 7
#define NB_ROWS  (1 << NB_SHIFT)   // 128 rows per bucket
#define GA 128                     // blocks for hist/bucket-scatter passes

// ---------------- hierarchical exclusive scan ----------------
template <int PT>
__global__ LB256 void gscan_sum(const int* __restrict__ a, int n, int* __restrict__ bsum) {
    int base = blockIdx.x * (256 * PT);
    int sum = 0;
    for (int i = threadIdx.x; i < 256 * PT; i += 256) {
        int idx = base + i;
        sum += (idx < n) ? a[idx] : 0;
    }
#pragma unroll
    for (int o = 32; o; o >>= 1) sum += __shfl_down(sum, o);
    __shared__ int ws[4];
    if ((threadIdx.x & 63) == 0) ws[threadIdx.x >> 6] = sum;
    __syncthreads();
    if (threadIdx.x == 0) bsum[blockIdx.x] = ws[0] + ws[1] + ws[2] + ws[3];
}

__global__ void gscan_offsets(const int* __restrict__ bsum, int nbk, int* __restrict__ boff) {
    int lane = threadIdx.x;
    int v = (lane < nbk) ? bsum[lane] : 0;
    int orig = v;
#pragma unroll
    for (int o = 1; o < 64; o <<= 1) {
        int u = __shfl_up(v, o);
        if (lane >= o) v += u;
    }
    if (lane < nbk) boff[lane] = v - orig;  // exclusive
}

template <int PT>
__global__ LB256 void gscan_scatter(const int* __restrict__ a, int n,
                                    const int* __restrict__ boff, int total,
                                    int* __restrict__ out1) {
    int base = blockIdx.x * (256 * PT);
    int idx0 = base + threadIdx.x * PT;
    int vals[PT];
    int s = 0;
#pragma unroll
    for (int k = 0; k < PT; ++k) {
        int id = idx0 + k;
        vals[k] = (id < n) ? a[id] : 0;
        s += vals[k];
    }
    int lane = threadIdx.x & 63, wid = threadIdx.x >> 6;
    int inc = s;
#pragma unroll
    for (int o = 1; o < 64; o <<= 1) {
        int u = __shfl_up(inc, o);
        if (lane >= o) inc += u;
    }
    __shared__ int wsum[4];
    if (lane == 63) wsum[wid] = inc;
    __syncthreads();
    int woff = 0;
    for (int i = 0; i < wid; ++i) woff += wsum[i];
    int excl = inc - s + woff + boff[blockIdx.x];
#pragma unroll
    for (int k = 0; k < PT; ++k) {
        int id = idx0 + k;
        if (id < n) out1[id] = excl;
        excl += vals[k];
    }
    if (blockIdx.x == 0 && threadIdx.x == 0) out1[n] = total;
}

// ---------------- CSR build (no global atomics) ----------------

__global__ LB256 void hist_kernel(const int* __restrict__ row, int E, int nb, int chunk,
                                  int* __restrict__ countmat) {
    __shared__ int lh[1024];
    for (int b = threadIdx.x; b < nb; b += 256) lh[b] = 0;
    __syncthreads();
    int beg = blockIdx.x * chunk;
    int end = min(E, beg + chunk);
    for (int i = beg + threadIdx.x; i < end; i += 256)
        atomicAdd(&lh[row[i] >> NB_SHIFT], 1);
    __syncthreads();
    for (int b = threadIdx.x; b < nb; b += 256)
        countmat[b * gridDim.x + blockIdx.x] = lh[b];
}

// tmpA = (wbits15<<17)|col  (final csr format), tmpB = rowlocal (u8)
__global__ LB256 void bucket_scatter_kernel(const int* __restrict__ row, const int* __restrict__ col,
                                            const float* __restrict__ w, const int* __restrict__ off,
                                            int E, int nb, int chunk,
                                            unsigned* __restrict__ tmpA,
                                            unsigned char* __restrict__ tmpB) {
    __shared__ int lc[1024];
    __shared__ int loff[1024];
    for (int b = threadIdx.x; b < nb; b += 256) {
        lc[b] = 0;
        loff[b] = off[b * gridDim.x + blockIdx.x];
    }
    __syncthreads();
    int beg = blockIdx.x * chunk;
    int end = min(E, beg + chunk);
    for (int i = beg + threadIdx.x; i < end; i += 256) {
        int r = row[i];
        int b = r >> NB_SHIFT;
        int lpos = atomicAdd(&lc[b], 1);
        unsigned wb = (__float_as_uint(w[i]) + 0x8000u) >> 16;  // bf16 RN bits (w>=0 -> 15 bits)
        int pos = loff[b] + lpos;
        tmpA[pos] = (wb << 17) | (unsigned)col[i];
        tmpB[pos] = (unsigned char)(r & (NB_ROWS - 1));
    }
}

// one block per 128-row bucket: LDS histogram -> scan -> rowptr + LDS-cursor scatter
__global__ LB256 void csr_build_kernel(const unsigned* __restrict__ tmpA,
                                       const unsigned char* __restrict__ tmpB,
                                       const int* __restrict__ off,
                                       int G, int N, int E,
                                       int* __restrict__ rowptr, unsigned* __restrict__ csr) {
    __shared__ int lcnt[NB_ROWS];
    __shared__ int wtot;
    int b = blockIdx.x;
    int tid = threadIdx.x;
    int s0 = off[b * G];
    int e0 = off[(b + 1) * G];
    int rbase = b << NB_SHIFT;

    if (tid < NB_ROWS) lcnt[tid] = 0;
    __syncthreads();
    for (int j = s0 + tid; j < e0; j += 256)
        atomicAdd(&lcnt[tmpB[j]], 1);
    __syncthreads();

    int val = 0, inc = 0;
    if (tid < NB_ROWS) {           // two waves: 0-63, 64-127
        val = lcnt[tid];
        inc = val;
        int lane = tid & 63;
#pragma unroll
        for (int o = 1; o < 64; o <<= 1) {
            int u = __shfl_up(inc, o);
            if (lane >= o) inc += u;
        }
        if (tid == 63) wtot = inc;
    }
    __syncthreads();
    if (tid < NB_ROWS) {
        int ex = inc - val + ((tid >= 64) ? wtot : 0);
        int idx = rbase + tid;
        if (idx < N) rowptr[idx] = s0 + ex;
        lcnt[tid] = ex;  // cursors
    }
    if (b == gridDim.x - 1 && tid == 0) rowptr[N] = E;
    __syncthreads();

    for (int j = s0 + tid; j < e0; j += 256) {
        unsigned a = tmpA[j];
        int pos = s0 + atomicAdd(&lcnt[tmpB[j]], 1);
        csr[pos] = a;
    }
}

// ---------------- per-layer kernels ----------------

// t (bf16) = h @ W^T, feature-split into halves of FH=min(FOUT,16)
template <int FIN, int FOUT>
__global__ LB256 void transform_kernel(const float* __restrict__ h, const float* __restrict__ W,
                                       __hip_bfloat16* __restrict__ t0,
                                       __hip_bfloat16* __restrict__ t1, int n) {
    constexpr int FH = (FOUT > 16) ? 16 : FOUT;
    int i = blockIdx.x * blockDim.x + threadIdx.x;
    if (i >= n * FOUT) return;
    int v = i / FOUT;
    int f = i % FOUT;
    float s = 0.0f;
#pragma unroll
    for (int k = 0; k < FIN; ++k) s = fmaf(h[v * FIN + k], W[f * FIN + k], s);
    __hip_bfloat16 bv = __float2bfloat16(s);
    if (f < FH) t0[v * FH + f] = bv;
    else        t1[v * FH + (f - FH)] = bv;
}

// gather-side aggregation; lane owns 2 features; GS lanes per row-group.
// csr entry: (wbits15<<17)|col ; th: [N][GS] bf16x2 words
template <int GS, int FTOT>
__global__ LB256 void agg_half_kernel(const int* __restrict__ rowptr,
                                      const unsigned* __restrict__ csr,
                                      const unsigned* __restrict__ th,
                                      const float* __restrict__ b, int fo,
                                      float* __restrict__ h, int N) {
    constexpr int RPB = 256 / GS;     // rows per block
    int g = threadIdx.x / GS;
    int l = threadIdx.x % GS;
    int v = blockIdx.x * RPB + g;
    if (v >= N) return;
    int beg = rowptr[v], end = rowptr[v + 1];
    float bf0 = b[fo + 2 * l];
    float bf1 = b[fo + 2 * l + 1];
    float a0 = 0.0f, a1 = 0.0f;

    int j = beg;
    for (; j + 7 < end; j += 8) {
        unsigned e[8];
#pragma unroll
        for (int u = 0; u < 8; ++u) e[u] = __builtin_nontemporal_load(&csr[j + u]);
        unsigned tv[8];
#pragma unroll
        for (int u = 0; u < 8; ++u) tv[u] = th[(e[u] & 0x1FFFFu) * GS + l];
#pragma unroll
        for (int u = 0; u < 8; ++u) {
            float wv = __uint_as_float((e[u] & 0xFFFE0000u) >> 1);
            float m0 = fmaf(wv, __uint_as_float(tv[u] << 16), bf0);
            float m1 = fmaf(wv, __uint_as_float(tv[u] & 0xffff0000u), bf1);
            a0 += (m0 > 0.f) ? m0 : 0.01f * m0;
            a1 += (m1 > 0.f) ? m1 : 0.01f * m1;
        }
    }
    for (; j < end; ++j) {
        unsigned e0 = __builtin_nontemporal_load(&csr[j]);
        unsigned t0 = th[(e0 & 0x1FFFFu) * GS + l];
        float wv = __uint_as_float((e0 & 0xFFFE0000u) >> 1);
        float m0 = fmaf(wv, __uint_as_float(t0 << 16), bf0);
        float m1 = fmaf(wv, __uint_as_float(t0 & 0xffff0000u), bf1);
        a0 += (m0 > 0.f) ? m0 : 0.01f * m0;
        a1 += (m1 > 0.f) ? m1 : 0.01f * m1;
    }

    int deg = end - beg;
    float iv = deg ? 1.0f / (float)deg : 0.0f;
    unsigned tr = th[v * GS + l];
    float r0 = __uint_as_float(tr << 16) + bf0;
    float r1 = __uint_as_float(tr & 0xffff0000u) + bf1;
    r0 = (r0 > 0.f) ? r0 : 0.01f * r0;
    r1 = (r1 > 0.f) ? r1 : 0.01f * r1;
    float2 st = make_float2(fmaf(a0, iv, r0), fmaf(a1, iv, r1));
    *(float2*)(h + (size_t)v * FTOT + fo + 2 * l) = st;
}

// ---------------- head ----------------

__global__ LB256 void pool_kernel(const float* __restrict__ h, float* __restrict__ pool, int n) {
    __shared__ float ls[256];
    int f = threadIdx.x & 31;
    int grp = threadIdx.x >> 5;
    int gid = blockIdx.x * (blockDim.x >> 5) + grp;
    int ngrp = (blockDim.x >> 5) * gridDim.x;
    float s = 0.0f;
    for (int v = gid; v < n; v += ngrp) s += h[v * 32 + f];
    ls[threadIdx.x] = s;
    __syncthreads();
    if (threadIdx.x < 32) {
        float tot = 0.0f;
#pragma unroll
        for (int g = 0; g < 8; ++g) tot += ls[g * 32 + threadIdx.x];
        atomicAdd(&pool[threadIdx.x], tot);
    }
}

__global__ void head_kernel(const float* __restrict__ pool, const float* __restrict__ W7,
                            const float* __restrict__ b7, float* __restrict__ out, int n) {
    if (threadIdx.x != 0 || blockIdx.x != 0) return;
    float invn = 1.0f / (float)n;
    float l0 = b7[0], l1 = b7[1];
    for (int f = 0; f < 32; ++f) {
        float p = pool[f] * invn;
        l0 = fmaf(p, W7[f], l0);
        l1 = fmaf(p, W7[32 + f], l1);
    }
    float m = fmaxf(l0, l1);
    float lse = m + logf(expf(l0 - m) + expf(l1 - m));
    out[0] = l0 - lse;
    out[1] = l1 - lse;
}

// ---------------- launch ----------------

extern "C" void kernel_launch(void* const* d_in, const int* in_sizes, int n_in,
                              void* d_out, int out_size, void* d_ws, size_t ws_size,
                              hipStream_t stream) {
    const float* x  = (const float*)d_in[0];
    const int* edge = (const int*)d_in[1];
    const float* w  = (const float*)d_in[2];
    const float* W1 = (const float*)d_in[3];
    const float* b1 = (const float*)d_in[4];
    const float* W3 = (const float*)d_in[5];
    const float* b3 = (const float*)d_in[6];
    const float* W5 = (const float*)d_in[7];
    const float* b5 = (const float*)d_in[8];
    const float* W7 = (const float*)d_in[9];
    const float* b7 = (const float*)d_in[10];
    float* out = (float*)d_out;

    const int N = in_sizes[0] / 4;
    const int E = in_sizes[1] / 2;
    const int* row = edge;
    const int* col = edge + E;

    const int nb = (N + NB_ROWS - 1) >> NB_SHIFT;    // 782 buckets of 128 rows
    const int G = GA;                                // 128
    const int chunk = (E + G - 1) / G;
    const int M = nb * G;                            // ~100k

    char* ws = (char*)d_ws;
    size_t off8 = 0;
    auto alloc = [&](size_t bytes) {
        void* p = ws + off8;
        off8 += (bytes + 255) & ~(size_t)255;
        return p;
    };
    int*      bsum     = (int*)alloc(256 * 4);
    int*      boff     = (int*)alloc(256 * 4);
    int*      countmat = (int*)alloc((size_t)M * 4);
    int*      offm     = (int*)alloc(((size_t)M + 1) * 4);
    int*      rowptr   = (int*)alloc(((size_t)N + 1) * 4);
    float*    pool     = (float*)alloc(32 * 4);
    unsigned* csr      = (unsigned*)alloc((size_t)E * 4);
    __hip_bfloat16* t0 = (__hip_bfloat16*)alloc((size_t)N * 16 * 2);
    __hip_bfloat16* t1 = (__hip_bfloat16*)alloc((size_t)N * 16 * 2);
    float*    h1       = (float*)alloc((size_t)N * 8 * 4);
    float*    h2       = (float*)alloc((size_t)N * 16 * 4);
    // tmpA (E*4) + tmpB (E) overlaid with h3 (N*32*4): tmp dead before layers
    size_t tmpsz = (size_t)E * 4 + 256 + (size_t)E;
    size_t h3sz  = (size_t)N * 32 * 4;
    char*  big   = (char*)alloc(tmpsz > h3sz ? tmpsz : h3sz);
    unsigned*      tmpA = (unsigned*)big;
    unsigned char* tmpB = (unsigned char*)(big + (((size_t)E * 4 + 255) & ~(size_t)255));
    float*         h3   = (float*)big;
    (void)ws_size;

    hipMemsetAsync(pool, 0, 32 * 4, stream);

    const int B = 256;
    const int nbkM = (M + 4095) / 4096;  // ~25 <= 64

    // CSR build
    hist_kernel<<<G, B, 0, stream>>>(row, E, nb, chunk, countmat);
    gscan_sum<16><<<nbkM, B, 0, stream>>>(countmat, M, bsum);
    gscan_offsets<<<1, 64, 0, stream>>>(bsum, nbkM, boff);
    gscan_scatter<16><<<nbkM, B, 0, stream>>>(countmat, M, boff, E, offm);
    bucket_scatter_kernel<<<G, B, 0, stream>>>(row, col, w, offm, E, nb, chunk, tmpA, tmpB);
    csr_build_kernel<<<nb, B, 0, stream>>>(tmpA, tmpB, offm, G, N, E, rowptr, csr);

    // ---- block 1: 4 -> 8 ----
    transform_kernel<4, 8><<<(N * 8 + B - 1) / B, B, 0, stream>>>(x, W1, t0, t0, N);
    agg_half_kernel<4, 8><<<(N + 63) / 64, B, 0, stream>>>(rowptr, csr, (const unsigned*)t0, b1, 0, h1, N);

    // ---- block 2: 8 -> 16 ----
    transform_kernel<8, 16><<<(N * 16 + B - 1) / B, B, 0, stream>>>(h1, W3, t0, t0, N);
    agg_half_kernel<8, 16><<<(N + 31) / 32, B, 0, stream>>>(rowptr, csr, (const unsigned*)t0, b3, 0, h2, N);

    // ---- block 3: 16 -> 32 (two independent 16-feature halves) ----
    transform_kernel<16, 32><<<(N * 32 + B - 1) / B, B, 0, stream>>>(h2, W5, t0, t1, N);
    agg_half_kernel<8, 32><<<(N + 31) / 32, B, 0, stream>>>(rowptr, csr, (const unsigned*)t0, b5, 0, h3, N);
    agg_half_kernel<8, 32><<<(N + 31) / 32, B, 0, stream>>>(rowptr, csr, (const unsigned*)t1, b5, 16, h3, N);

    // ---- head ----
    pool_kernel<<<256, B, 0, stream>>>(h3, pool, N);
    head_kernel<<<1, 64, 0, stream>>>(pool, W7, b7, out, N);
}

// Round 11
// 407.680 us; speedup vs baseline: 3.4606x; 1.0750x over previous
//
#include <hip/hip_runtime.h>
#include <hip/hip_bf16.h>
#include <math.h>

#define LB256 __launch_bounds__(256)

#define NB_SHIFT 8
#define NB_ROWS  (1 << NB_SHIFT)   // 256 rows per bucket
#define GA 512                     // blocks for hist/bucket-scatter passes

// ---------------- hierarchical exclusive scan ----------------
template <int PT>
__global__ LB256 void gscan_sum(const int* __restrict__ a, int n, int* __restrict__ bsum) {
    int base = blockIdx.x * (256 * PT);
    int sum = 0;
    for (int i = threadIdx.x; i < 256 * PT; i += 256) {
        int idx = base + i;
        sum += (idx < n) ? a[idx] : 0;
    }
#pragma unroll
    for (int o = 32; o; o >>= 1) sum += __shfl_down(sum, o);
    __shared__ int ws[4];
    if ((threadIdx.x & 63) == 0) ws[threadIdx.x >> 6] = sum;
    __syncthreads();
    if (threadIdx.x == 0) bsum[blockIdx.x] = ws[0] + ws[1] + ws[2] + ws[3];
}

__global__ void gscan_offsets(const int* __restrict__ bsum, int nbk, int* __restrict__ boff) {
    int lane = threadIdx.x;
    int v = (lane < nbk) ? bsum[lane] : 0;
    int orig = v;
#pragma unroll
    for (int o = 1; o < 64; o <<= 1) {
        int u = __shfl_up(v, o);
        if (lane >= o) v += u;
    }
    if (lane < nbk) boff[lane] = v - orig;  // exclusive
}

template <int PT>
__global__ LB256 void gscan_scatter(const int* __restrict__ a, int n,
                                    const int* __restrict__ boff, int total,
                                    int* __restrict__ out1) {
    int base = blockIdx.x * (256 * PT);
    int idx0 = base + threadIdx.x * PT;
    int vals[PT];
    int s = 0;
#pragma unroll
    for (int k = 0; k < PT; ++k) {
        int id = idx0 + k;
        vals[k] = (id < n) ? a[id] : 0;
        s += vals[k];
    }
    int lane = threadIdx.x & 63, wid = threadIdx.x >> 6;
    int inc = s;
#pragma unroll
    for (int o = 1; o < 64; o <<= 1) {
        int u = __shfl_up(inc, o);
        if (lane >= o) inc += u;
    }
    __shared__ int wsum[4];
    if (lane == 63) wsum[wid] = inc;
    __syncthreads();
    int woff = 0;
    for (int i = 0; i < wid; ++i) woff += wsum[i];
    int excl = inc - s + woff + boff[blockIdx.x];
#pragma unroll
    for (int k = 0; k < PT; ++k) {
        int id = idx0 + k;
        if (id < n) out1[id] = excl;
        excl += vals[k];
    }
    if (blockIdx.x == 0 && threadIdx.x == 0) out1[n] = total;
}

// ---------------- CSR build (no global atomics) ----------------

__global__ LB256 void hist_kernel(const int* __restrict__ row, int E, int nb, int chunk,
                                  int* __restrict__ countmat) {
    __shared__ int lh[512];
    for (int b = threadIdx.x; b < nb; b += 256) lh[b] = 0;
    __syncthreads();
    int beg = blockIdx.x * chunk;
    int end = min(E, beg + chunk);
    for (int i = beg + threadIdx.x; i < end; i += 256)
        atomicAdd(&lh[row[i] >> NB_SHIFT], 1);
    __syncthreads();
    for (int b = threadIdx.x; b < nb; b += 256)
        countmat[b * gridDim.x + blockIdx.x] = lh[b];
}

// tmpA = (wbits15<<17)|col  (final csr format), tmpB = rowlocal (u8)
__global__ LB256 void bucket_scatter_kernel(const int* __restrict__ row, const int* __restrict__ col,
                                            const float* __restrict__ w, const int* __restrict__ off,
                                            int E, int nb, int chunk,
                                            unsigned* __restrict__ tmpA,
                                            unsigned char* __restrict__ tmpB) {
    __shared__ int lc[512];
    __shared__ int loff[512];
    for (int b = threadIdx.x; b < nb; b += 256) {
        lc[b] = 0;
        loff[b] = off[b * gridDim.x + blockIdx.x];
    }
    __syncthreads();
    int beg = blockIdx.x * chunk;
    int end = min(E, beg + chunk);
    for (int i = beg + threadIdx.x; i < end; i += 256) {
        int r = row[i];
        int b = r >> NB_SHIFT;
        int lpos = atomicAdd(&lc[b], 1);
        unsigned wb = (__float_as_uint(w[i]) + 0x8000u) >> 16;  // bf16 RN bits (w>=0 -> 15 bits)
        int pos = loff[b] + lpos;
        tmpA[pos] = (wb << 17) | (unsigned)col[i];
        tmpB[pos] = (unsigned char)(r & (NB_ROWS - 1));
    }
}

// one block per 256-row bucket: LDS histogram -> 4-wave scan -> rowptr + LDS-cursor scatter
__global__ LB256 void csr_build_kernel(const unsigned* __restrict__ tmpA,
                                       const unsigned char* __restrict__ tmpB,
                                       const int* __restrict__ off,
                                       int G, int N, int E,
                                       int* __restrict__ rowptr, unsigned* __restrict__ csr) {
    __shared__ int lcnt[NB_ROWS];
    __shared__ int wsum[4];
    int b = blockIdx.x;
    int tid = threadIdx.x;
    int s0 = off[b * G];
    int e0 = off[(b + 1) * G];
    int rbase = b << NB_SHIFT;

    lcnt[tid] = 0;
    __syncthreads();
    for (int j = s0 + tid; j < e0; j += 256)
        atomicAdd(&lcnt[tmpB[j]], 1);
    __syncthreads();

    int val = lcnt[tid];
    int lane = tid & 63, wid = tid >> 6;
    int inc = val;
#pragma unroll
    for (int o = 1; o < 64; o <<= 1) {
        int u = __shfl_up(inc, o);
        if (lane >= o) inc += u;
    }
    if (lane == 63) wsum[wid] = inc;
    __syncthreads();
    int woff = 0;
    for (int i = 0; i < wid; ++i) woff += wsum[i];
    int ex = inc - val + woff;

    int idx = rbase + tid;
    if (idx < N) rowptr[idx] = s0 + ex;
    if (b == gridDim.x - 1 && tid == 0) rowptr[N] = E;
    __syncthreads();
    lcnt[tid] = ex;  // cursors
    __syncthreads();

    for (int j = s0 + tid; j < e0; j += 256) {
        unsigned a = tmpA[j];
        int pos = s0 + atomicAdd(&lcnt[tmpB[j]], 1);
        csr[pos] = a;
    }
}

// ---------------- per-layer kernels ----------------

// t (bf16) = h @ W^T, feature-split into halves of FH=min(FOUT,16)
template <int FIN, int FOUT>
__global__ LB256 void transform_kernel(const float* __restrict__ h, const float* __restrict__ W,
                                       __hip_bfloat16* __restrict__ t0,
                                       __hip_bfloat16* __restrict__ t1, int n) {
    constexpr int FH = (FOUT > 16) ? 16 : FOUT;
    int i = blockIdx.x * blockDim.x + threadIdx.x;
    if (i >= n * FOUT) return;
    int v = i / FOUT;
    int f = i % FOUT;
    float s = 0.0f;
#pragma unroll
    for (int k = 0; k < FIN; ++k) s = fmaf(h[v * FIN + k], W[f * FIN + k], s);
    __hip_bfloat16 bv = __float2bfloat16(s);
    if (f < FH) t0[v * FH + f] = bv;
    else        t1[v * FH + (f - FH)] = bv;
}

// gather-side aggregation; lane owns 2 features; GS lanes per row-group.
// csr entry: (wbits15<<17)|col ; th: [N][GS] bf16x2 words
template <int GS, int FTOT>
__global__ LB256 void agg_half_kernel(const int* __restrict__ rowptr,
                                      const unsigned* __restrict__ csr,
                                      const unsigned* __restrict__ th,
                                      const float* __restrict__ b, int fo,
                                      float* __restrict__ h, int N) {
    constexpr int RPB = 256 / GS;     // rows per block
    int g = threadIdx.x / GS;
    int l = threadIdx.x % GS;
    int v = blockIdx.x * RPB + g;
    if (v >= N) return;
    int beg = rowptr[v], end = rowptr[v + 1];
    float bf0 = b[fo + 2 * l];
    float bf1 = b[fo + 2 * l + 1];
    float a0 = 0.0f, a1 = 0.0f;

    int j = beg;
    for (; j + 7 < end; j += 8) {
        unsigned e[8];
#pragma unroll
        for (int u = 0; u < 8; ++u) e[u] = __builtin_nontemporal_load(&csr[j + u]);
        unsigned tv[8];
#pragma unroll
        for (int u = 0; u < 8; ++u) tv[u] = th[(e[u] & 0x1FFFFu) * GS + l];
#pragma unroll
        for (int u = 0; u < 8; ++u) {
            float wv = __uint_as_float((e[u] & 0xFFFE0000u) >> 1);
            float m0 = fmaf(wv, __uint_as_float(tv[u] << 16), bf0);
            float m1 = fmaf(wv, __uint_as_float(tv[u] & 0xffff0000u), bf1);
            a0 += (m0 > 0.f) ? m0 : 0.01f * m0;
            a1 += (m1 > 0.f) ? m1 : 0.01f * m1;
        }
    }
    for (; j < end; ++j) {
        unsigned e0 = __builtin_nontemporal_load(&csr[j]);
        unsigned t0 = th[(e0 & 0x1FFFFu) * GS + l];
        float wv = __uint_as_float((e0 & 0xFFFE0000u) >> 1);
        float m0 = fmaf(wv, __uint_as_float(t0 << 16), bf0);
        float m1 = fmaf(wv, __uint_as_float(t0 & 0xffff0000u), bf1);
        a0 += (m0 > 0.f) ? m0 : 0.01f * m0;
        a1 += (m1 > 0.f) ? m1 : 0.01f * m1;
    }

    int deg = end - beg;
    float iv = deg ? 1.0f / (float)deg : 0.0f;
    unsigned tr = th[v * GS + l];
    float r0 = __uint_as_float(tr << 16) + bf0;
    float r1 = __uint_as_float(tr & 0xffff0000u) + bf1;
    r0 = (r0 > 0.f) ? r0 : 0.01f * r0;
    r1 = (r1 > 0.f) ? r1 : 0.01f * r1;
    float2 st = make_float2(fmaf(a0, iv, r0), fmaf(a1, iv, r1));
    *(float2*)(h + (size_t)v * FTOT + fo + 2 * l) = st;
}

// ---------------- head ----------------

__global__ LB256 void pool_kernel(const float* __restrict__ h, float* __restrict__ pool, int n) {
    __shared__ float ls[256];
    int f = threadIdx.x & 31;
    int grp = threadIdx.x >> 5;
    int gid = blockIdx.x * (blockDim.x >> 5) + grp;
    int ngrp = (blockDim.x >> 5) * gridDim.x;
    float s = 0.0f;
    for (int v = gid; v < n; v += ngrp) s += h[v * 32 + f];
    ls[threadIdx.x] = s;
    __syncthreads();
    if (threadIdx.x < 32) {
        float tot = 0.0f;
#pragma unroll
        for (int g = 0; g < 8; ++g) tot += ls[g * 32 + threadIdx.x];
        atomicAdd(&pool[threadIdx.x], tot);
    }
}

__global__ void head_kernel(const float* __restrict__ pool, const float* __restrict__ W7,
                            const float* __restrict__ b7, float* __restrict__ out, int n) {
    if (threadIdx.x != 0 || blockIdx.x != 0) return;
    float invn = 1.0f / (float)n;
    float l0 = b7[0], l1 = b7[1];
    for (int f = 0; f < 32; ++f) {
        float p = pool[f] * invn;
        l0 = fmaf(p, W7[f], l0);
        l1 = fmaf(p, W7[32 + f], l1);
    }
    float m = fmaxf(l0, l1);
    float lse = m + logf(expf(l0 - m) + expf(l1 - m));
    out[0] = l0 - lse;
    out[1] = l1 - lse;
}

// ---------------- launch ----------------

extern "C" void kernel_launch(void* const* d_in, const int* in_sizes, int n_in,
                              void* d_out, int out_size, void* d_ws, size_t ws_size,
                              hipStream_t stream) {
    const float* x  = (const float*)d_in[0];
    const int* edge = (const int*)d_in[1];
    const float* w  = (const float*)d_in[2];
    const float* W1 = (const float*)d_in[3];
    const float* b1 = (const float*)d_in[4];
    const float* W3 = (const float*)d_in[5];
    const float* b3 = (const float*)d_in[6];
    const float* W5 = (const float*)d_in[7];
    const float* b5 = (const float*)d_in[8];
    const float* W7 = (const float*)d_in[9];
    const float* b7 = (const float*)d_in[10];
    float* out = (float*)d_out;

    const int N = in_sizes[0] / 4;
    const int E = in_sizes[1] / 2;
    const int* row = edge;
    const int* col = edge + E;

    const int nb = (N + NB_ROWS - 1) >> NB_SHIFT;    // 391 buckets of 256 rows
    const int G = GA;                                // 512
    const int chunk = (E + G - 1) / G;               // 6250
    const int M = nb * G;                            // ~200k

    char* ws = (char*)d_ws;
    size_t off8 = 0;
    auto alloc = [&](size_t bytes) {
        void* p = ws + off8;
        off8 += (bytes + 255) & ~(size_t)255;
        return p;
    };
    int*      bsum     = (int*)alloc(256 * 4);
    int*      boff     = (int*)alloc(256 * 4);
    int*      countmat = (int*)alloc((size_t)M * 4);
    int*      offm     = (int*)alloc(((size_t)M + 1) * 4);
    int*      rowptr   = (int*)alloc(((size_t)N + 1) * 4);
    float*    pool     = (float*)alloc(32 * 4);
    unsigned* csr      = (unsigned*)alloc((size_t)E * 4);
    __hip_bfloat16* t0 = (__hip_bfloat16*)alloc((size_t)N * 16 * 2);
    __hip_bfloat16* t1 = (__hip_bfloat16*)alloc((size_t)N * 16 * 2);
    float*    h1       = (float*)alloc((size_t)N * 8 * 4);
    float*    h2       = (float*)alloc((size_t)N * 16 * 4);
    // tmpA (E*4) + tmpB (E) overlaid with h3 (N*32*4): tmp dead before layers
    size_t tmpsz = (size_t)E * 4 + 256 + (size_t)E;
    size_t h3sz  = (size_t)N * 32 * 4;
    char*  big   = (char*)alloc(tmpsz > h3sz ? tmpsz : h3sz);
    unsigned*      tmpA = (unsigned*)big;
    unsigned char* tmpB = (unsigned char*)(big + (((size_t)E * 4 + 255) & ~(size_t)255));
    float*         h3   = (float*)big;
    (void)ws_size;

    hipMemsetAsync(pool, 0, 32 * 4, stream);

    const int B = 256;
    const int nbkM = (M + 4095) / 4096;  // 49 <= 64

    // CSR build
    hist_kernel<<<G, B, 0, stream>>>(row, E, nb, chunk, countmat);
    gscan_sum<16><<<nbkM, B, 0, stream>>>(countmat, M, bsum);
    gscan_offsets<<<1, 64, 0, stream>>>(bsum, nbkM, boff);
    gscan_scatter<16><<<nbkM, B, 0, stream>>>(countmat, M, boff, E, offm);
    bucket_scatter_kernel<<<G, B, 0, stream>>>(row, col, w, offm, E, nb, chunk, tmpA, tmpB);
    csr_build_kernel<<<nb, B, 0, stream>>>(tmpA, tmpB, offm, G, N, E, rowptr, csr);

    // ---- block 1: 4 -> 8 ----
    transform_kernel<4, 8><<<(N * 8 + B - 1) / B, B, 0, stream>>>(x, W1, t0, t0, N);
    agg_half_kernel<4, 8><<<(N + 63) / 64, B, 0, stream>>>(rowptr, csr, (const unsigned*)t0, b1, 0, h1, N);

    // ---- block 2: 8 -> 16 ----
    transform_kernel<8, 16><<<(N * 16 + B - 1) / B, B, 0, stream>>>(h1, W3, t0, t0, N);
    agg_half_kernel<8, 16><<<(N + 31) / 32, B, 0, stream>>>(rowptr, csr, (const unsigned*)t0, b3, 0, h2, N);

    // ---- block 3: 16 -> 32 (two independent 16-feature halves) ----
    transform_kernel<16, 32><<<(N * 32 + B - 1) / B, B, 0, stream>>>(h2, W5, t0, t1, N);
    agg_half_kernel<8, 32><<<(N + 31) / 32, B, 0, stream>>>(rowptr, csr, (const unsigned*)t0, b5, 0, h3, N);
    agg_half_kernel<8, 32><<<(N + 31) / 32, B, 0, stream>>>(rowptr, csr, (const unsigned*)t1, b5, 16, h3, N);

    // ---- head ----
    pool_kernel<<<256, B, 0, stream>>>(h3, pool, N);
    head_kernel<<<1, 64, 0, stream>>>(pool, W7, b7, out, N);
}

// Round 12
// 366.930 us; speedup vs baseline: 3.8449x; 1.1111x over previous
//
#include <hip/hip_runtime.h>
#include <hip/hip_bf16.h>
#include <math.h>

#define LB256 __launch_bounds__(256)

#define NB_SHIFT 8
#define NB_ROWS  (1 << NB_SHIFT)   // 256 rows per bucket
#define GA 512                     // blocks for hist/scatter passes
#define TILE 2048                  // edges per sort tile

// ---------------- hierarchical exclusive scan ----------------
template <int PT>
__global__ LB256 void gscan_sum(const int* __restrict__ a, int n, int* __restrict__ bsum) {
    int base = blockIdx.x * (256 * PT);
    int sum = 0;
    for (int i = threadIdx.x; i < 256 * PT; i += 256) {
        int idx = base + i;
        sum += (idx < n) ? a[idx] : 0;
    }
#pragma unroll
    for (int o = 32; o; o >>= 1) sum += __shfl_down(sum, o);
    __shared__ int ws[4];
    if ((threadIdx.x & 63) == 0) ws[threadIdx.x >> 6] = sum;
    __syncthreads();
    if (threadIdx.x == 0) bsum[blockIdx.x] = ws[0] + ws[1] + ws[2] + ws[3];
}

__global__ void gscan_offsets(const int* __restrict__ bsum, int nbk, int* __restrict__ boff) {
    int lane = threadIdx.x;
    int v = (lane < nbk) ? bsum[lane] : 0;
    int orig = v;
#pragma unroll
    for (int o = 1; o < 64; o <<= 1) {
        int u = __shfl_up(v, o);
        if (lane >= o) v += u;
    }
    if (lane < nbk) boff[lane] = v - orig;  // exclusive
}

template <int PT>
__global__ LB256 void gscan_scatter(const int* __restrict__ a, int n,
                                    const int* __restrict__ boff, int total,
                                    int* __restrict__ out1) {
    int base = blockIdx.x * (256 * PT);
    int idx0 = base + threadIdx.x * PT;
    int vals[PT];
    int s = 0;
#pragma unroll
    for (int k = 0; k < PT; ++k) {
        int id = idx0 + k;
        vals[k] = (id < n) ? a[id] : 0;
        s += vals[k];
    }
    int lane = threadIdx.x & 63, wid = threadIdx.x >> 6;
    int inc = s;
#pragma unroll
    for (int o = 1; o < 64; o <<= 1) {
        int u = __shfl_up(inc, o);
        if (lane >= o) inc += u;
    }
    __shared__ int wsum[4];
    if (lane == 63) wsum[wid] = inc;
    __syncthreads();
    int woff = 0;
    for (int i = 0; i < wid; ++i) woff += wsum[i];
    int excl = inc - s + woff + boff[blockIdx.x];
#pragma unroll
    for (int k = 0; k < PT; ++k) {
        int id = idx0 + k;
        if (id < n) out1[id] = excl;
        excl += vals[k];
    }
    if (blockIdx.x == 0 && threadIdx.x == 0) out1[n] = total;
}

// ---------------- CSR build (no global atomics) ----------------

__global__ LB256 void hist_kernel(const int* __restrict__ row, int E, int nb, int chunk,
                                  int* __restrict__ countmat) {
    __shared__ int lh[512];
    for (int b = threadIdx.x; b < 512; b += 256) lh[b] = 0;
    __syncthreads();
    int beg = blockIdx.x * chunk;
    int end = min(E, beg + chunk);
    for (int i = beg + threadIdx.x; i < end; i += 256)
        atomicAdd(&lh[row[i] >> NB_SHIFT], 1);
    __syncthreads();
    for (int b = threadIdx.x; b < nb; b += 256)
        countmat[b * gridDim.x + blockIdx.x] = lh[b];
}

// tile-ranked scatter: per 2048-edge tile, rank entries by bucket in LDS, then
// wave-coalesced write-out. entry u64 = bucket<<40 | rowlocal<<32 | wbits15<<17 | col
__global__ LB256 void sort_scatter_kernel(const int* __restrict__ row, const int* __restrict__ col,
                                          const float* __restrict__ w, const int* __restrict__ off,
                                          int E, int G, int chunk,
                                          unsigned long long* __restrict__ tmp) {
    __shared__ unsigned long long stage[TILE];
    __shared__ int lh[512];
    __shared__ int seg[512];
    __shared__ int gcur[512];
    __shared__ int wsum[4];
    int blk = blockIdx.x, tid = threadIdx.x;
    int beg = blk * chunk, end = min(E, beg + chunk);
    for (int b = tid; b < 512; b += 256) {
        gcur[b] = off[b * G + blk];
        lh[b] = 0;
    }
    __syncthreads();

    for (int tbase = beg; tbase < end; tbase += TILE) {
        int tcnt = min(TILE, end - tbase);
        int bk[8], sl[8];
        unsigned long long en[8];
#pragma unroll
        for (int k = 0; k < 8; ++k) {
            int e = tbase + k * 256 + tid;
            bk[k] = -1;
            if (e < end) {
                int r = row[e];
                int b = r >> NB_SHIFT;
                unsigned wb = (__float_as_uint(w[e]) + 0x8000u) >> 16;  // bf16 RN bits, w>=0
                en[k] = ((unsigned long long)b << 40) |
                        ((unsigned long long)(r & (NB_ROWS - 1)) << 32) |
                        (unsigned long long)((wb << 17) | (unsigned)col[e]);
                bk[k] = b;
                sl[k] = atomicAdd(&lh[b], 1);
            }
        }
        __syncthreads();
        // exclusive scan of lh[0..511] -> seg
        int c0 = lh[2 * tid], c1 = lh[2 * tid + 1];
        int tsum = c0 + c1;
        int lane = tid & 63, wid = tid >> 6;
        int inc = tsum;
#pragma unroll
        for (int o = 1; o < 64; o <<= 1) {
            int u = __shfl_up(inc, o);
            if (lane >= o) inc += u;
        }
        if (lane == 63) wsum[wid] = inc;
        __syncthreads();
        int woff = 0;
        for (int i = 0; i < wid; ++i) woff += wsum[i];
        int ex = inc - tsum + woff;
        seg[2 * tid] = ex;
        seg[2 * tid + 1] = ex + c0;
        __syncthreads();
        // place into stage ordered by bucket
#pragma unroll
        for (int k = 0; k < 8; ++k)
            if (bk[k] >= 0) stage[seg[bk[k]] + sl[k]] = en[k];
        __syncthreads();
        // coalesced write-out: consecutive lanes -> consecutive dests within segments
        for (int p = tid; p < tcnt; p += 256) {
            unsigned long long ent = stage[p];
            int b = (int)(ent >> 40);
            tmp[gcur[b] + (p - seg[b])] = ent;
        }
        __syncthreads();
        for (int b = tid; b < 512; b += 256) {
            gcur[b] += lh[b];
            lh[b] = 0;
        }
        __syncthreads();
    }
}

// one block per 256-row bucket: LDS histogram -> 4-wave scan -> rowptr + LDS-cursor scatter
__global__ LB256 void csr_build_kernel(const unsigned long long* __restrict__ tmp,
                                       const int* __restrict__ off,
                                       int G, int N, int E,
                                       int* __restrict__ rowptr, unsigned* __restrict__ csr) {
    __shared__ int lcnt[NB_ROWS];
    __shared__ int wsum[4];
    int b = blockIdx.x;
    int tid = threadIdx.x;
    int s0 = off[b * G];
    int e0 = off[(b + 1) * G];
    int rbase = b << NB_SHIFT;

    lcnt[tid] = 0;
    __syncthreads();
    for (int j = s0 + tid; j < e0; j += 256)
        atomicAdd(&lcnt[(int)((tmp[j] >> 32) & 0xFFu)], 1);
    __syncthreads();

    int val = lcnt[tid];
    int lane = tid & 63, wid = tid >> 6;
    int inc = val;
#pragma unroll
    for (int o = 1; o < 64; o <<= 1) {
        int u = __shfl_up(inc, o);
        if (lane >= o) inc += u;
    }
    if (lane == 63) wsum[wid] = inc;
    __syncthreads();
    int woff = 0;
    for (int i = 0; i < wid; ++i) woff += wsum[i];
    int ex = inc - val + woff;

    int idx = rbase + tid;
    if (idx < N) rowptr[idx] = s0 + ex;
    if (b == gridDim.x - 1 && tid == 0) rowptr[N] = E;
    __syncthreads();
    lcnt[tid] = ex;  // cursors
    __syncthreads();

    for (int j = s0 + tid; j < e0; j += 256) {
        unsigned long long ent = tmp[j];
        int pos = s0 + atomicAdd(&lcnt[(int)((ent >> 32) & 0xFFu)], 1);
        csr[pos] = (unsigned)ent;
    }
}

// ---------------- per-layer kernels ----------------

// t (bf16) = h @ W^T, feature-split into halves of FH=min(FOUT,16)
template <int FIN, int FOUT>
__global__ LB256 void transform_kernel(const float* __restrict__ h, const float* __restrict__ W,
                                       __hip_bfloat16* __restrict__ t0,
                                       __hip_bfloat16* __restrict__ t1, int n) {
    constexpr int FH = (FOUT > 16) ? 16 : FOUT;
    int i = blockIdx.x * blockDim.x + threadIdx.x;
    if (i >= n * FOUT) return;
    int v = i / FOUT;
    int f = i % FOUT;
    float s = 0.0f;
#pragma unroll
    for (int k = 0; k < FIN; ++k) s = fmaf(h[v * FIN + k], W[f * FIN + k], s);
    __hip_bfloat16 bv = __float2bfloat16(s);
    if (f < FH) t0[v * FH + f] = bv;
    else        t1[v * FH + (f - FH)] = bv;
}

// gather-side aggregation; lane owns 2 features; GS lanes per row-group.
// csr entry: (wbits15<<17)|col ; th: [N][GS] bf16x2 words
template <int GS, int FTOT>
__global__ LB256 void agg_half_kernel(const int* __restrict__ rowptr,
                                      const unsigned* __restrict__ csr,
                                      const unsigned* __restrict__ th,
                                      const float* __restrict__ b, int fo,
                                      float* __restrict__ h, int N) {
    constexpr int RPB = 256 / GS;     // rows per block
    int g = threadIdx.x / GS;
    int l = threadIdx.x % GS;
    int v = blockIdx.x * RPB + g;
    if (v >= N) return;
    int beg = rowptr[v], end = rowptr[v + 1];
    float bf0 = b[fo + 2 * l];
    float bf1 = b[fo + 2 * l + 1];
    float a0 = 0.0f, a1 = 0.0f;

    int j = beg;
    for (; j + 7 < end; j += 8) {
        unsigned e[8];
#pragma unroll
        for (int u = 0; u < 8; ++u) e[u] = __builtin_nontemporal_load(&csr[j + u]);
        unsigned tv[8];
#pragma unroll
        for (int u = 0; u < 8; ++u) tv[u] = th[(e[u] & 0x1FFFFu) * GS + l];
#pragma unroll
        for (int u = 0; u < 8; ++u) {
            float wv = __uint_as_float((e[u] & 0xFFFE0000u) >> 1);
            float m0 = fmaf(wv, __uint_as_float(tv[u] << 16), bf0);
            float m1 = fmaf(wv, __uint_as_float(tv[u] & 0xffff0000u), bf1);
            a0 += (m0 > 0.f) ? m0 : 0.01f * m0;
            a1 += (m1 > 0.f) ? m1 : 0.01f * m1;
        }
    }
    for (; j < end; ++j) {
        unsigned e0 = __builtin_nontemporal_load(&csr[j]);
        unsigned t0 = th[(e0 & 0x1FFFFu) * GS + l];
        float wv = __uint_as_float((e0 & 0xFFFE0000u) >> 1);
        float m0 = fmaf(wv, __uint_as_float(t0 << 16), bf0);
        float m1 = fmaf(wv, __uint_as_float(t0 & 0xffff0000u), bf1);
        a0 += (m0 > 0.f) ? m0 : 0.01f * m0;
        a1 += (m1 > 0.f) ? m1 : 0.01f * m1;
    }

    int deg = end - beg;
    float iv = deg ? 1.0f / (float)deg : 0.0f;
    unsigned tr = th[v * GS + l];
    float r0 = __uint_as_float(tr << 16) + bf0;
    float r1 = __uint_as_float(tr & 0xffff0000u) + bf1;
    r0 = (r0 > 0.f) ? r0 : 0.01f * r0;
    r1 = (r1 > 0.f) ? r1 : 0.01f * r1;
    float2 st = make_float2(fmaf(a0, iv, r0), fmaf(a1, iv, r1));
    *(float2*)(h + (size_t)v * FTOT + fo + 2 * l) = st;
}

// ---------------- head ----------------

__global__ LB256 void pool_kernel(const float* __restrict__ h, float* __restrict__ pool, int n) {
    __shared__ float ls[256];
    int f = threadIdx.x & 31;
    int grp = threadIdx.x >> 5;
    int gid = blockIdx.x * (blockDim.x >> 5) + grp;
    int ngrp = (blockDim.x >> 5) * gridDim.x;
    float s = 0.0f;
    for (int v = gid; v < n; v += ngrp) s += h[v * 32 + f];
    ls[threadIdx.x] = s;
    __syncthreads();
    if (threadIdx.x < 32) {
        float tot = 0.0f;
#pragma unroll
        for (int g = 0; g < 8; ++g) tot += ls[g * 32 + threadIdx.x];
        atomicAdd(&pool[threadIdx.x], tot);
    }
}

__global__ void head_kernel(const float* __restrict__ pool, const float* __restrict__ W7,
                            const float* __restrict__ b7, float* __restrict__ out, int n) {
    if (threadIdx.x != 0 || blockIdx.x != 0) return;
    float invn = 1.0f / (float)n;
    float l0 = b7[0], l1 = b7[1];
    for (int f = 0; f < 32; ++f) {
        float p = pool[f] * invn;
        l0 = fmaf(p, W7[f], l0);
        l1 = fmaf(p, W7[32 + f], l1);
    }
    float m = fmaxf(l0, l1);
    float lse = m + logf(expf(l0 - m) + expf(l1 - m));
    out[0] = l0 - lse;
    out[1] = l1 - lse;
}

// ---------------- launch ----------------

extern "C" void kernel_launch(void* const* d_in, const int* in_sizes, int n_in,
                              void* d_out, int out_size, void* d_ws, size_t ws_size,
                              hipStream_t stream) {
    const float* x  = (const float*)d_in[0];
    const int* edge = (const int*)d_in[1];
    const float* w  = (const float*)d_in[2];
    const float* W1 = (const float*)d_in[3];
    const float* b1 = (const float*)d_in[4];
    const float* W3 = (const float*)d_in[5];
    const float* b3 = (const float*)d_in[6];
    const float* W5 = (const float*)d_in[7];
    const float* b5 = (const float*)d_in[8];
    const float* W7 = (const float*)d_in[9];
    const float* b7 = (const float*)d_in[10];
    float* out = (float*)d_out;

    const int N = in_sizes[0] / 4;
    const int E = in_sizes[1] / 2;
    const int* row = edge;
    const int* col = edge + E;

    const int nb = (N + NB_ROWS - 1) >> NB_SHIFT;    // 391 buckets of 256 rows
    const int G = GA;                                // 512
    const int chunk = (E + G - 1) / G;               // 6250
    const int M = nb * G;                            // ~200k

    char* ws = (char*)d_ws;
    size_t off8 = 0;
    auto alloc = [&](size_t bytes) {
        void* p = ws + off8;
        off8 += (bytes + 255) & ~(size_t)255;
        return p;
    };
    int*      bsum     = (int*)alloc(256 * 4);
    int*      boff     = (int*)alloc(256 * 4);
    int*      countmat = (int*)alloc((size_t)M * 4);
    int*      offm     = (int*)alloc(((size_t)M + 1) * 4);
    int*      rowptr   = (int*)alloc(((size_t)N + 1) * 4);
    float*    pool     = (float*)alloc(32 * 4);
    unsigned* csr      = (unsigned*)alloc((size_t)E * 4);
    __hip_bfloat16* t0 = (__hip_bfloat16*)alloc((size_t)N * 16 * 2);
    __hip_bfloat16* t1 = (__hip_bfloat16*)alloc((size_t)N * 16 * 2);
    float*    h1       = (float*)alloc((size_t)N * 8 * 4);
    float*    h2       = (float*)alloc((size_t)N * 16 * 4);
    // tmp (E*8 = 25.6MB) overlaid with h3 (N*32*4 = 12.8MB): tmp dead before layers
    size_t tmpsz = (size_t)E * 8;
    size_t h3sz  = (size_t)N * 32 * 4;
    char*  big   = (char*)alloc(tmpsz > h3sz ? tmpsz : h3sz);
    unsigned long long* tmp = (unsigned long long*)big;
    float*              h3  = (float*)big;
    (void)ws_size;

    hipMemsetAsync(pool, 0, 32 * 4, stream);

    const int B = 256;
    const int nbkM = (M + 4095) / 4096;  // 49 <= 64

    // CSR build
    hist_kernel<<<G, B, 0, stream>>>(row, E, nb, chunk, countmat);
    gscan_sum<16><<<nbkM, B, 0, stream>>>(countmat, M, bsum);
    gscan_offsets<<<1, 64, 0, stream>>>(bsum, nbkM, boff);
    gscan_scatter<16><<<nbkM, B, 0, stream>>>(countmat, M, boff, E, offm);
    sort_scatter_kernel<<<G, B, 0, stream>>>(row, col, w, offm, E, G, chunk, tmp);
    csr_build_kernel<<<nb, B, 0, stream>>>(tmp, offm, G, N, E, rowptr, csr);

    // ---- block 1: 4 -> 8 ----
    transform_kernel<4, 8><<<(N * 8 + B - 1) / B, B, 0, stream>>>(x, W1, t0, t0, N);
    agg_half_kernel<4, 8><<<(N + 63) / 64, B, 0, stream>>>(rowptr, csr, (const unsigned*)t0, b1, 0, h1, N);

    // ---- block 2: 8 -> 16 ----
    transform_kernel<8, 16><<<(N * 16 + B - 1) / B, B, 0, stream>>>(h1, W3, t0, t0, N);
    agg_half_kernel<8, 16><<<(N + 31) / 32, B, 0, stream>>>(rowptr, csr, (const unsigned*)t0, b3, 0, h2, N);

    // ---- block 3: 16 -> 32 (two independent 16-feature halves) ----
    transform_kernel<16, 32><<<(N * 32 + B - 1) / B, B, 0, stream>>>(h2, W5, t0, t1, N);
    agg_half_kernel<8, 32><<<(N + 31) / 32, B, 0, stream>>>(rowptr, csr, (const unsigned*)t0, b5, 0, h3, N);
    agg_half_kernel<8, 32><<<(N + 31) / 32, B, 0, stream>>>(rowptr, csr, (const unsigned*)t1, b5, 16, h3, N);

    // ---- head ----
    pool_kernel<<<256, B, 0, stream>>>(h3, pool, N);
    head_kernel<<<1, 64, 0, stream>>>(pool, W7, b7, out, N);
}

// Round 14
// 354.342 us; speedup vs baseline: 3.9815x; 1.0355x over previous
//
#include <hip/hip_runtime.h>
#include <hip/hip_bf16.h>
#include <math.h>

// NOTE: identical to round-13 submission — that round hit a GPU-acquisition
// timeout (infra), the kernel never executed. Resubmitting for a clean bench.

#define LB256 __launch_bounds__(256)

#define NB_SHIFT 8
#define NB_ROWS  (1 << NB_SHIFT)   // 256 rows per bucket
#define GA 512                     // blocks for hist/scatter passes
#define TILE 2048                  // edges per sort tile
#define CBCAP 12288                // csr_build LDS stage capacity (seg ~8192±90)

// ---------------- hierarchical exclusive scan ----------------
template <int PT>
__global__ LB256 void gscan_sum(const int* __restrict__ a, int n, int* __restrict__ bsum) {
    int base = blockIdx.x * (256 * PT);
    int sum = 0;
    for (int i = threadIdx.x; i < 256 * PT; i += 256) {
        int idx = base + i;
        sum += (idx < n) ? a[idx] : 0;
    }
#pragma unroll
    for (int o = 32; o; o >>= 1) sum += __shfl_down(sum, o);
    __shared__ int ws[4];
    if ((threadIdx.x & 63) == 0) ws[threadIdx.x >> 6] = sum;
    __syncthreads();
    if (threadIdx.x == 0) bsum[blockIdx.x] = ws[0] + ws[1] + ws[2] + ws[3];
}

__global__ void gscan_offsets(const int* __restrict__ bsum, int nbk, int* __restrict__ boff) {
    int lane = threadIdx.x;
    int v = (lane < nbk) ? bsum[lane] : 0;
    int orig = v;
#pragma unroll
    for (int o = 1; o < 64; o <<= 1) {
        int u = __shfl_up(v, o);
        if (lane >= o) v += u;
    }
    if (lane < nbk) boff[lane] = v - orig;  // exclusive
}

template <int PT>
__global__ LB256 void gscan_scatter(const int* __restrict__ a, int n,
                                    const int* __restrict__ boff, int total,
                                    int* __restrict__ out1) {
    int base = blockIdx.x * (256 * PT);
    int idx0 = base + threadIdx.x * PT;
    int vals[PT];
    int s = 0;
#pragma unroll
    for (int k = 0; k < PT; ++k) {
        int id = idx0 + k;
        vals[k] = (id < n) ? a[id] : 0;
        s += vals[k];
    }
    int lane = threadIdx.x & 63, wid = threadIdx.x >> 6;
    int inc = s;
#pragma unroll
    for (int o = 1; o < 64; o <<= 1) {
        int u = __shfl_up(inc, o);
        if (lane >= o) inc += u;
    }
    __shared__ int wsum[4];
    if (lane == 63) wsum[wid] = inc;
    __syncthreads();
    int woff = 0;
    for (int i = 0; i < wid; ++i) woff += wsum[i];
    int excl = inc - s + woff + boff[blockIdx.x];
#pragma unroll
    for (int k = 0; k < PT; ++k) {
        int id = idx0 + k;
        if (id < n) out1[id] = excl;
        excl += vals[k];
    }
    if (blockIdx.x == 0 && threadIdx.x == 0) out1[n] = total;
}

// ---------------- CSR build (no global atomics) ----------------

__global__ LB256 void hist_kernel(const int* __restrict__ row, int E, int nb, int chunk,
                                  int* __restrict__ countmat) {
    __shared__ int lh[512];
    for (int b = threadIdx.x; b < 512; b += 256) lh[b] = 0;
    __syncthreads();
    int beg = blockIdx.x * chunk;
    int end = min(E, beg + chunk);
    for (int i = beg + threadIdx.x; i < end; i += 256)
        atomicAdd(&lh[row[i] >> NB_SHIFT], 1);
    __syncthreads();
    for (int b = threadIdx.x; b < nb; b += 256)
        countmat[b * gridDim.x + blockIdx.x] = lh[b];
}

// tile-ranked scatter: per 2048-edge tile, rank entries by bucket in LDS, then
// wave-coalesced write-out. entry u64 = bucket<<40 | rowlocal<<32 | wbits15<<17 | col
__global__ LB256 void sort_scatter_kernel(const int* __restrict__ row, const int* __restrict__ col,
                                          const float* __restrict__ w, const int* __restrict__ off,
                                          int E, int G, int chunk,
                                          unsigned long long* __restrict__ tmp) {
    __shared__ unsigned long long stage[TILE];
    __shared__ int lh[512];
    __shared__ int seg[512];
    __shared__ int gcur[512];
    __shared__ int wsum[4];
    int blk = blockIdx.x, tid = threadIdx.x;
    int beg = blk * chunk, end = min(E, beg + chunk);
    for (int b = tid; b < 512; b += 256) {
        gcur[b] = off[b * G + blk];
        lh[b] = 0;
    }
    __syncthreads();

    for (int tbase = beg; tbase < end; tbase += TILE) {
        int tcnt = min(TILE, end - tbase);
        int bk[8], sl[8];
        unsigned long long en[8];
#pragma unroll
        for (int k = 0; k < 8; ++k) {
            int e = tbase + k * 256 + tid;
            bk[k] = -1;
            if (e < end) {
                int r = row[e];
                int b = r >> NB_SHIFT;
                unsigned wb = (__float_as_uint(w[e]) + 0x8000u) >> 16;  // bf16 RN bits, w>=0
                en[k] = ((unsigned long long)b << 40) |
                        ((unsigned long long)(r & (NB_ROWS - 1)) << 32) |
                        (unsigned long long)((wb << 17) | (unsigned)col[e]);
                bk[k] = b;
                sl[k] = atomicAdd(&lh[b], 1);
            }
        }
        __syncthreads();
        // exclusive scan of lh[0..511] -> seg
        int c0 = lh[2 * tid], c1 = lh[2 * tid + 1];
        int tsum = c0 + c1;
        int lane = tid & 63, wid = tid >> 6;
        int inc = tsum;
#pragma unroll
        for (int o = 1; o < 64; o <<= 1) {
            int u = __shfl_up(inc, o);
            if (lane >= o) inc += u;
        }
        if (lane == 63) wsum[wid] = inc;
        __syncthreads();
        int woff = 0;
        for (int i = 0; i < wid; ++i) woff += wsum[i];
        int ex = inc - tsum + woff;
        seg[2 * tid] = ex;
        seg[2 * tid + 1] = ex + c0;
        __syncthreads();
        // place into stage ordered by bucket
#pragma unroll
        for (int k = 0; k < 8; ++k)
            if (bk[k] >= 0) stage[seg[bk[k]] + sl[k]] = en[k];
        __syncthreads();
        // coalesced write-out
        for (int p = tid; p < tcnt; p += 256) {
            unsigned long long ent = stage[p];
            int b = (int)(ent >> 40);
            tmp[gcur[b] + (p - seg[b])] = ent;
        }
        __syncthreads();
        for (int b = tid; b < 512; b += 256) {
            gcur[b] += lh[b];
            lh[b] = 0;
        }
        __syncthreads();
    }
}

// one block per 256-row bucket: histogram -> scan -> rowptr; then rank into LDS
// stage and write csr linearly (coalesced).
__global__ LB256 void csr_build_kernel(const unsigned long long* __restrict__ tmp,
                                       const int* __restrict__ off,
                                       int G, int N, int E,
                                       int* __restrict__ rowptr, unsigned* __restrict__ csr) {
    __shared__ int lcnt[NB_ROWS];
    __shared__ int wsum[4];
    __shared__ unsigned stage[CBCAP];
    int b = blockIdx.x;
    int tid = threadIdx.x;
    int s0 = off[b * G];
    int e0 = off[(b + 1) * G];
    int seg = e0 - s0;
    int rbase = b << NB_SHIFT;

    lcnt[tid] = 0;
    __syncthreads();
    for (int j = s0 + tid; j < e0; j += 256)
        atomicAdd(&lcnt[(int)((tmp[j] >> 32) & 0xFFu)], 1);
    __syncthreads();

    int val = lcnt[tid];
    int lane = tid & 63, wid = tid >> 6;
    int inc = val;
#pragma unroll
    for (int o = 1; o < 64; o <<= 1) {
        int u = __shfl_up(inc, o);
        if (lane >= o) inc += u;
    }
    if (lane == 63) wsum[wid] = inc;
    __syncthreads();
    int woff = 0;
    for (int i = 0; i < wid; ++i) woff += wsum[i];
    int ex = inc - val + woff;

    int idx = rbase + tid;
    if (idx < N) rowptr[idx] = s0 + ex;
    if (b == gridDim.x - 1 && tid == 0) rowptr[N] = E;
    __syncthreads();
    lcnt[tid] = ex;  // cursors (bucket-local)
    __syncthreads();

    if (seg <= CBCAP) {
        for (int j = s0 + tid; j < e0; j += 256) {
            unsigned long long ent = tmp[j];
            int pos = atomicAdd(&lcnt[(int)((ent >> 32) & 0xFFu)], 1);
            stage[pos] = (unsigned)ent;
        }
        __syncthreads();
        for (int p = tid; p < seg; p += 256) csr[s0 + p] = stage[p];
    } else {  // overflow fallback (statistically unreachable)
        for (int j = s0 + tid; j < e0; j += 256) {
            unsigned long long ent = tmp[j];
            int pos = s0 + atomicAdd(&lcnt[(int)((ent >> 32) & 0xFFu)], 1);
            csr[pos] = (unsigned)ent;
        }
    }
}

// ---------------- per-layer kernels ----------------

// t (bf16) = h @ W^T, feature-split into halves of FH=min(FOUT,16)
template <int FIN, int FOUT>
__global__ LB256 void transform_kernel(const float* __restrict__ h, const float* __restrict__ W,
                                       __hip_bfloat16* __restrict__ t0,
                                       __hip_bfloat16* __restrict__ t1, int n) {
    constexpr int FH = (FOUT > 16) ? 16 : FOUT;
    int i = blockIdx.x * blockDim.x + threadIdx.x;
    if (i >= n * FOUT) return;
    int v = i / FOUT;
    int f = i % FOUT;
    float s = 0.0f;
#pragma unroll
    for (int k = 0; k < FIN; ++k) s = fmaf(h[v * FIN + k], W[f * FIN + k], s);
    __hip_bfloat16 bv = __float2bfloat16(s);
    if (f < FH) t0[v * FH + f] = bv;
    else        t1[v * FH + (f - FH)] = bv;
}

// gather-side aggregation; lane owns 2 features; GS lanes per row-group.
// csr entry: (wbits15<<17)|col ; th: [N][GS] bf16x2 words. 16-deep gather ILP.
template <int GS, int FTOT>
__global__ LB256 void agg_half_kernel(const int* __restrict__ rowptr,
                                      const unsigned* __restrict__ csr,
                                      const unsigned* __restrict__ th,
                                      const float* __restrict__ b, int fo,
                                      float* __restrict__ h, int N) {
    constexpr int RPB = 256 / GS;     // rows per block
    int g = threadIdx.x / GS;
    int l = threadIdx.x % GS;
    int v = blockIdx.x * RPB + g;
    if (v >= N) return;
    int beg = rowptr[v], end = rowptr[v + 1];
    float bf0 = b[fo + 2 * l];
    float bf1 = b[fo + 2 * l + 1];
    float a0 = 0.0f, a1 = 0.0f;

    int j = beg;
    for (; j + 15 < end; j += 16) {
        unsigned e[16];
#pragma unroll
        for (int u = 0; u < 16; ++u) e[u] = __builtin_nontemporal_load(&csr[j + u]);
        unsigned tv[16];
#pragma unroll
        for (int u = 0; u < 16; ++u) tv[u] = th[(e[u] & 0x1FFFFu) * GS + l];
#pragma unroll
        for (int u = 0; u < 16; ++u) {
            float wv = __uint_as_float((e[u] & 0xFFFE0000u) >> 1);
            float m0 = fmaf(wv, __uint_as_float(tv[u] << 16), bf0);
            float m1 = fmaf(wv, __uint_as_float(tv[u] & 0xffff0000u), bf1);
            a0 += (m0 > 0.f) ? m0 : 0.01f * m0;
            a1 += (m1 > 0.f) ? m1 : 0.01f * m1;
        }
    }
    for (; j + 3 < end; j += 4) {
        unsigned e[4];
#pragma unroll
        for (int u = 0; u < 4; ++u) e[u] = __builtin_nontemporal_load(&csr[j + u]);
        unsigned tv[4];
#pragma unroll
        for (int u = 0; u < 4; ++u) tv[u] = th[(e[u] & 0x1FFFFu) * GS + l];
#pragma unroll
        for (int u = 0; u < 4; ++u) {
            float wv = __uint_as_float((e[u] & 0xFFFE0000u) >> 1);
            float m0 = fmaf(wv, __uint_as_float(tv[u] << 16), bf0);
            float m1 = fmaf(wv, __uint_as_float(tv[u] & 0xffff0000u), bf1);
            a0 += (m0 > 0.f) ? m0 : 0.01f * m0;
            a1 += (m1 > 0.f) ? m1 : 0.01f * m1;
        }
    }
    for (; j < end; ++j) {
        unsigned e0 = __builtin_nontemporal_load(&csr[j]);
        unsigned t0 = th[(e0 & 0x1FFFFu) * GS + l];
        float wv = __uint_as_float((e0 & 0xFFFE0000u) >> 1);
        float m0 = fmaf(wv, __uint_as_float(t0 << 16), bf0);
        float m1 = fmaf(wv, __uint_as_float(t0 & 0xffff0000u), bf1);
        a0 += (m0 > 0.f) ? m0 : 0.01f * m0;
        a1 += (m1 > 0.f) ? m1 : 0.01f * m1;
    }

    int deg = end - beg;
    float iv = deg ? 1.0f / (float)deg : 0.0f;
    unsigned tr = th[v * GS + l];
    float r0 = __uint_as_float(tr << 16) + bf0;
    float r1 = __uint_as_float(tr & 0xffff0000u) + bf1;
    r0 = (r0 > 0.f) ? r0 : 0.01f * r0;
    r1 = (r1 > 0.f) ? r1 : 0.01f * r1;
    float2 st = make_float2(fmaf(a0, iv, r0), fmaf(a1, iv, r1));
    *(float2*)(h + (size_t)v * FTOT + fo + 2 * l) = st;
}

// ---------------- head ----------------

__global__ LB256 void pool_kernel(const float* __restrict__ h, float* __restrict__ pool, int n) {
    __shared__ float ls[256];
    int f = threadIdx.x & 31;
    int grp = threadIdx.x >> 5;
    int gid = blockIdx.x * (blockDim.x >> 5) + grp;
    int ngrp = (blockDim.x >> 5) * gridDim.x;
    float s = 0.0f;
    for (int v = gid; v < n; v += ngrp) s += h[v * 32 + f];
    ls[threadIdx.x] = s;
    __syncthreads();
    if (threadIdx.x < 32) {
        float tot = 0.0f;
#pragma unroll
        for (int g = 0; g < 8; ++g) tot += ls[g * 32 + threadIdx.x];
        atomicAdd(&pool[threadIdx.x], tot);
    }
}

__global__ void head_kernel(const float* __restrict__ pool, const float* __restrict__ W7,
                            const float* __restrict__ b7, float* __restrict__ out, int n) {
    if (threadIdx.x != 0 || blockIdx.x != 0) return;
    float invn = 1.0f / (float)n;
    float l0 = b7[0], l1 = b7[1];
    for (int f = 0; f < 32; ++f) {
        float p = pool[f] * invn;
        l0 = fmaf(p, W7[f], l0);
        l1 = fmaf(p, W7[32 + f], l1);
    }
    float m = fmaxf(l0, l1);
    float lse = m + logf(expf(l0 - m) + expf(l1 - m));
    out[0] = l0 - lse;
    out[1] = l1 - lse;
}

// ---------------- launch ----------------

extern "C" void kernel_launch(void* const* d_in, const int* in_sizes, int n_in,
                              void* d_out, int out_size, void* d_ws, size_t ws_size,
                              hipStream_t stream) {
    const float* x  = (const float*)d_in[0];
    const int* edge = (const int*)d_in[1];
    const float* w  = (const float*)d_in[2];
    const float* W1 = (const float*)d_in[3];
    const float* b1 = (const float*)d_in[4];
    const float* W3 = (const float*)d_in[5];
    const float* b3 = (const float*)d_in[6];
    const float* W5 = (const float*)d_in[7];
    const float* b5 = (const float*)d_in[8];
    const float* W7 = (const float*)d_in[9];
    const float* b7 = (const float*)d_in[10];
    float* out = (float*)d_out;

    const int N = in_sizes[0] / 4;
    const int E = in_sizes[1] / 2;
    const int* row = edge;
    const int* col = edge + E;

    const int nb = (N + NB_ROWS - 1) >> NB_SHIFT;    // 391 buckets of 256 rows
    const int G = GA;                                // 512
    const int chunk = (E + G - 1) / G;               // 6250
    const int M = nb * G;                            // ~200k

    char* ws = (char*)d_ws;
    size_t off8 = 0;
    auto alloc = [&](size_t bytes) {
        void* p = ws + off8;
        off8 += (bytes + 255) & ~(size_t)255;
        return p;
    };
    int*      bsum     = (int*)alloc(256 * 4);
    int*      boff     = (int*)alloc(256 * 4);
    int*      countmat = (int*)alloc((size_t)M * 4);
    int*      offm     = (int*)alloc(((size_t)M + 1) * 4);
    int*      rowptr   = (int*)alloc(((size_t)N + 1) * 4);
    float*    pool     = (float*)alloc(32 * 4);
    unsigned* csr      = (unsigned*)alloc((size_t)E * 4);
    __hip_bfloat16* t0 = (__hip_bfloat16*)alloc((size_t)N * 16 * 2);
    __hip_bfloat16* t1 = (__hip_bfloat16*)alloc((size_t)N * 16 * 2);
    float*    h1       = (float*)alloc((size_t)N * 8 * 4);
    float*    h2       = (float*)alloc((size_t)N * 16 * 4);
    // tmp (E*8 = 25.6MB) overlaid with h3 (N*32*4 = 12.8MB): tmp dead before layers
    size_t tmpsz = (size_t)E * 8;
    size_t h3sz  = (size_t)N * 32 * 4;
    char*  big   = (char*)alloc(tmpsz > h3sz ? tmpsz : h3sz);
    unsigned long long* tmp = (unsigned long long*)big;
    float*              h3  = (float*)big;
    (void)ws_size;

    hipMemsetAsync(pool, 0, 32 * 4, stream);

    const int B = 256;
    const int nbkM = (M + 4095) / 4096;  // 49 <= 64

    // CSR build
    hist_kernel<<<G, B, 0, stream>>>(row, E, nb, chunk, countmat);
    gscan_sum<16><<<nbkM, B, 0, stream>>>(countmat, M, bsum);
    gscan_offsets<<<1, 64, 0, stream>>>(bsum, nbkM, boff);
    gscan_scatter<16><<<nbkM, B, 0, stream>>>(countmat, M, boff, E, offm);
    sort_scatter_kernel<<<G, B, 0, stream>>>(row, col, w, offm, E, G, chunk, tmp);
    csr_build_kernel<<<nb, B, 0, stream>>>(tmp, offm, G, N, E, rowptr, csr);

    // ---- block 1: 4 -> 8 ----
    transform_kernel<4, 8><<<(N * 8 + B - 1) / B, B, 0, stream>>>(x, W1, t0, t0, N);
    agg_half_kernel<4, 8><<<(N + 63) / 64, B, 0, stream>>>(rowptr, csr, (const unsigned*)t0, b1, 0, h1, N);

    // ---- block 2: 8 -> 16 ----
    transform_kernel<8, 16><<<(N * 16 + B - 1) / B, B, 0, stream>>>(h1, W3, t0, t0, N);
    agg_half_kernel<8, 16><<<(N + 31) / 32, B, 0, stream>>>(rowptr, csr, (const unsigned*)t0, b3, 0, h2, N);

    // ---- block 3: 16 -> 32 (two independent 16-feature halves) ----
    transform_kernel<16, 32><<<(N * 32 + B - 1) / B, B, 0, stream>>>(h2, W5, t0, t1, N);
    agg_half_kernel<8, 32><<<(N + 31) / 32, B, 0, stream>>>(rowptr, csr, (const unsigned*)t0, b5, 0, h3, N);
    agg_half_kernel<8, 32><<<(N + 31) / 32, B, 0, stream>>>(rowptr, csr, (const unsigned*)t1, b5, 16, h3, N);

    // ---- head ----
    pool_kernel<<<256, B, 0, stream>>>(h3, pool, N);
    head_kernel<<<1, 64, 0, stream>>>(pool, W7, b7, out, N);
}